// Round 4
// baseline (1262.387 us; speedup 1.0000x reference)
//
#include <hip/hip_runtime.h>
#include <hip/hip_fp16.h>
#include <math.h>

// Problem constants (from reference)
#define BS    8
#define NE    4800
#define NN    4981
#define CIN   3
#define HD    128      // H
#define DBLK  6        // D processor blocks
#define NEDGE 153600   // BS*EPG
#define NTOT  38400    // BS*NE (graph nodes)
#define NMESH (BS*NN)  // 39848 mesh rows

typedef _Float16 f16;
typedef _Float16 f16x8 __attribute__((ext_vector_type(8)));
typedef float f32x4 __attribute__((ext_vector_type(4)));

__device__ __forceinline__ float lrelu(float x) { return x >= 0.0f ? x : 0.2f * x; }

// ---------------------------------------------------------------------------
// K0: hv0 = ln(mlp(enc_clnb_row, enc_ew1..3), enc_elng, enc_elnb)
// Conv encoder + LayerNorm over size-1 axis collapses exactly to enc_clnb.
// ---------------------------------------------------------------------------
__global__ __launch_bounds__(128)
void enc_const_kernel(const float* __restrict__ clnb,
                      const float* __restrict__ ew1, const float* __restrict__ eb1,
                      const float* __restrict__ ew2, const float* __restrict__ eb2,
                      const float* __restrict__ ew3,
                      const float* __restrict__ g, const float* __restrict__ b,
                      float* __restrict__ hv0) {
    __shared__ float s1[HD], s2[HD], s3[HD];
    int j = threadIdx.x;
    float a = eb1[j];
    for (int c = 0; c < CIN; ++c) a += clnb[c] * ew1[c * HD + j];
    s1[j] = lrelu(a);
    __syncthreads();
    a = eb2[j];
    for (int k = 0; k < HD; ++k) a += s1[k] * ew2[k * HD + j];
    s2[j] = lrelu(a);
    __syncthreads();
    a = 0.0f;
    for (int k = 0; k < HD; ++k) a += s2[k] * ew3[k * HD + j];
    s3[j] = a;
    __syncthreads();
    float m = 0.0f;
    for (int k = 0; k < HD; ++k) m += s3[k];
    m *= (1.0f / HD);
    float v = 0.0f;
    for (int k = 0; k < HD; ++k) { float d = s3[k] - m; v += d * d; }
    v *= (1.0f / HD);
    float rs = 1.0f / sqrtf(v + 1e-5f);
    hv0[j] = (s3[j] - m) * rs * g[j] + b[j];
}

// Broadcast hv0 (fp32) to all NTOT node rows as f16
__global__ __launch_bounds__(256)
void init_h16_kernel(f16* __restrict__ h, const float* __restrict__ hv0, int n8) {
    __shared__ f16 v[HD];
    if (threadIdx.x < HD) v[threadIdx.x] = (f16)hv0[threadIdx.x];
    __syncthreads();
    for (int i = blockIdx.x * blockDim.x + threadIdx.x; i < n8; i += gridDim.x * blockDim.x)
        ((uint4*)h)[i] = ((const uint4*)v)[i & 15];
}

// ---------------------------------------------------------------------------
// Convert + transpose processor weights to f16 Wt[n][k] layout.
// 48 matrices of 128x128: per d: eW1a,eW1b,eW2,eW3,nW1a,nW1b,nW2,nW3
// ---------------------------------------------------------------------------
__global__ __launch_bounds__(256)
void conv_weights_kernel(const float* __restrict__ ew1, const float* __restrict__ ew2,
                         const float* __restrict__ ew3,
                         const float* __restrict__ nw1, const float* __restrict__ nw2,
                         const float* __restrict__ nw3, f16* __restrict__ wbuf) {
    int b = blockIdx.x;        // 0..47
    int d = b >> 3, m = b & 7;
    const float* src;
    switch (m) {
        case 0: src = ew1 + (size_t)d * 2 * HD * HD; break;
        case 1: src = ew1 + (size_t)d * 2 * HD * HD + HD * HD; break;
        case 2: src = ew2 + (size_t)d * HD * HD; break;
        case 3: src = ew3 + (size_t)d * HD * HD; break;
        case 4: src = nw1 + (size_t)d * 2 * HD * HD; break;
        case 5: src = nw1 + (size_t)d * 2 * HD * HD + HD * HD; break;
        case 6: src = nw2 + (size_t)d * HD * HD; break;
        default: src = nw3 + (size_t)d * HD * HD; break;
    }
    f16* out = wbuf + (size_t)b * HD * HD;
    for (int idx = threadIdx.x; idx < HD * HD; idx += 256) {
        int n = idx >> 7, k = idx & 127;
        out[idx] = (f16)src[k * HD + n];   // Wt[n][k] = W[k][n]
    }
}

// ---------------------------------------------------------------------------
// Fused GraphNet MLP tile kernel on MFMA (fp16 in, fp32 accumulate).
// B-fragments come from global (Wt rows are L2-resident) but are BATCH-
// PREFETCHED into VGPRs per K-pass: one load burst -> one waitcnt -> 32 MFMAs,
// instead of 16 latency-serialized load->mfma pairs (the round-3 regression).
// MODE 0 = edge: A1=h[dest], A2=h[src]; LN out -> packed-f16 atomics to aggr.
// MODE 1 = node: A1=h[row],  A2=aggr16[row]; LN out -> h_out f16.
// Tile 64 rows x 128 cols, 4 waves; wave w: rows (w>>1)*32, cols (w&1)*64,
// 2x4 grid of 16x16x32 MFMA. A[m=lane&15][k=quad*8+j], C/D col=lane&15,
// row=quad*4+reg (guide-verified). LDS ~36 KB -> 4 blocks/CU.
// ---------------------------------------------------------------------------
__device__ __forceinline__ void gemm_k128_pf(const f16 (*A)[HD + 8], const f16* __restrict__ Wg,
                                             int rt_base, int ct_base, int ln, int quad,
                                             f32x4 acc[2][4]) {
    // Phase 1: batch-load all 16 B fragments (no dependencies -> issued back-to-back)
    f16x8 bfr[4][4];
    #pragma unroll
    for (int ks = 0; ks < 4; ++ks) {
        int kb = ks * 32 + quad * 8;
        #pragma unroll
        for (int c = 0; c < 4; ++c)
            bfr[ks][c] = *(const f16x8*)(Wg + (size_t)(ct_base + c * 16 + ln) * HD + kb);
    }
    // Phase 2: MFMA chain (A from LDS, B from registers)
    #pragma unroll
    for (int ks = 0; ks < 4; ++ks) {
        int kb = ks * 32 + quad * 8;
        f16x8 a0 = *(const f16x8*)(&A[rt_base + ln][kb]);
        f16x8 a1 = *(const f16x8*)(&A[rt_base + 16 + ln][kb]);
        #pragma unroll
        for (int c = 0; c < 4; ++c) {
            acc[0][c] = __builtin_amdgcn_mfma_f32_16x16x32_f16(a0, bfr[ks][c], acc[0][c], 0, 0, 0);
            acc[1][c] = __builtin_amdgcn_mfma_f32_16x16x32_f16(a1, bfr[ks][c], acc[1][c], 0, 0, 0);
        }
    }
}

template <int MODE>
__global__ __launch_bounds__(256, 4)
void gn_mfma(const f16* __restrict__ h16, const f16* __restrict__ aggr_in,
             const int* __restrict__ dest, const int* __restrict__ src,
             const f16* __restrict__ W1a, const f16* __restrict__ W1b,
             const f16* __restrict__ W2, const f16* __restrict__ W3,
             const float* __restrict__ b1, const float* __restrict__ b2,
             const float* __restrict__ g, const float* __restrict__ bln,
             f16* __restrict__ aggr_out, f16* __restrict__ h_out) {
    __shared__ __align__(16) f16 As1[64][HD + 8];
    __shared__ __align__(16) f16 As2[64][HD + 8];
    __shared__ float red[64][2][2];
    __shared__ int dS[64], sS[64];

    const int tid = threadIdx.x;
    const int base = blockIdx.x * 64;
    const int wave = tid >> 6;
    const int lane = tid & 63;
    const int ln = lane & 15;
    const int quad = lane >> 4;
    const int rt_base = (wave >> 1) * 32;
    const int ct_base = (wave & 1) * 64;
    const int half = wave & 1;

    if (MODE == 0) {
        if (tid < 64) dS[tid] = dest[base + tid];
        else if (tid < 128) sS[tid - 64] = src[base + tid - 64];
        __syncthreads();
    }

    // ---- Stage A tiles (f16, 16B chunks: 64 rows x 16 chunks per tile)
    #pragma unroll
    for (int t = 0; t < 4; ++t) {
        int idx = tid + t * 256;            // 0..1023
        int r = idx >> 4, c = (idx & 15) * 8;
        if (MODE == 0) {
            *(uint4*)(&As1[r][c]) = *(const uint4*)(h16 + (size_t)dS[r] * HD + c);
            *(uint4*)(&As2[r][c]) = *(const uint4*)(h16 + (size_t)sS[r] * HD + c);
        } else {
            *(uint4*)(&As1[r][c]) = *(const uint4*)(h16 + (size_t)(base + r) * HD + c);
            *(uint4*)(&As2[r][c]) = *(const uint4*)(aggr_in + (size_t)(base + r) * HD + c);
        }
    }
    __syncthreads();

    f32x4 acc[2][4];

    // ---- Layer 1: K=256 over [As1 | As2], bias b1, lrelu
    #pragma unroll
    for (int c = 0; c < 4; ++c) {
        float bj = b1[ct_base + c * 16 + ln];
        f32x4 bb = {bj, bj, bj, bj};
        acc[0][c] = bb; acc[1][c] = bb;
    }
    gemm_k128_pf(As1, W1a, rt_base, ct_base, ln, quad, acc);
    gemm_k128_pf(As2, W1b, rt_base, ct_base, ln, quad, acc);
    __syncthreads();          // all As1/As2 reads done
    #pragma unroll
    for (int i = 0; i < 2; ++i)
        #pragma unroll
        for (int c = 0; c < 4; ++c)
            #pragma unroll
            for (int r = 0; r < 4; ++r)
                As1[rt_base + i * 16 + quad * 4 + r][ct_base + c * 16 + ln] =
                    (f16)lrelu(acc[i][c][r]);
    __syncthreads();          // act1 visible

    // ---- Layer 2: K=128 over As1, bias b2, lrelu
    #pragma unroll
    for (int c = 0; c < 4; ++c) {
        float bj = b2[ct_base + c * 16 + ln];
        f32x4 bb = {bj, bj, bj, bj};
        acc[0][c] = bb; acc[1][c] = bb;
    }
    gemm_k128_pf(As1, W2, rt_base, ct_base, ln, quad, acc);
    __syncthreads();          // As1 reads done before As2 rewrite readers sync
    #pragma unroll
    for (int i = 0; i < 2; ++i)
        #pragma unroll
        for (int c = 0; c < 4; ++c)
            #pragma unroll
            for (int r = 0; r < 4; ++r)
                As2[rt_base + i * 16 + quad * 4 + r][ct_base + c * 16 + ln] =
                    (f16)lrelu(acc[i][c][r]);
    __syncthreads();          // act2 visible

    // ---- Layer 3: K=128 over As2, no bias/activation
    #pragma unroll
    for (int c = 0; c < 4; ++c) {
        f32x4 z = {0.f, 0.f, 0.f, 0.f};
        acc[0][c] = z; acc[1][c] = z;
    }
    gemm_k128_pf(As2, W3, rt_base, ct_base, ln, quad, acc);

    // ---- LayerNorm stats: quad-level shfl reduce (xor 1,2,4,8 stay in-quad),
    // combine the two column-halves through LDS
    #pragma unroll
    for (int i = 0; i < 2; ++i)
        #pragma unroll
        for (int r = 0; r < 4; ++r) {
            float s = acc[i][0][r] + acc[i][1][r] + acc[i][2][r] + acc[i][3][r];
            float q = acc[i][0][r] * acc[i][0][r] + acc[i][1][r] * acc[i][1][r] +
                      acc[i][2][r] * acc[i][2][r] + acc[i][3][r] * acc[i][3][r];
            s += __shfl_xor(s, 1); q += __shfl_xor(q, 1);
            s += __shfl_xor(s, 2); q += __shfl_xor(q, 2);
            s += __shfl_xor(s, 4); q += __shfl_xor(q, 4);
            s += __shfl_xor(s, 8); q += __shfl_xor(q, 8);
            if (ln == 0) {
                int row = rt_base + i * 16 + quad * 4 + r;
                red[row][half][0] = s;
                red[row][half][1] = q;
            }
        }
    __syncthreads();

    // ---- Epilogue: LN scale + packed-f16 atomics (edge) or f16 store (node)
    float gv[4], bv[4];
    #pragma unroll
    for (int c = 0; c < 4; ++c) {
        int col = ct_base + c * 16 + ln;
        gv[c] = g[col]; bv[c] = bln[col];
    }
    #pragma unroll
    for (int i = 0; i < 2; ++i)
        #pragma unroll
        for (int r = 0; r < 4; ++r) {
            int row = rt_base + i * 16 + quad * 4 + r;
            float s = red[row][0][0] + red[row][1][0];
            float q = red[row][0][1] + red[row][1][1];
            float m = s * (1.0f / HD);
            float var = q * (1.0f / HD) - m * m;
            float rs = 1.0f / sqrtf(var + 1e-5f);
            #pragma unroll
            for (int c = 0; c < 4; ++c) {
                int col = ct_base + c * 16 + ln;
                float v = (acc[i][c][r] - m) * rs * gv[c] + bv[c];
                if (MODE == 0) {
                    float pv = __shfl_xor(v, 1);   // partner col (ln^1)
                    if (!(ln & 1)) {
                        __half2 h2 = __floats2half2_rn(v, pv);
                        unsafeAtomicAdd((__half2*)(aggr_out + (size_t)dS[row] * HD + col),
                                        h2);
                    }
                } else {
                    h_out[(size_t)(base + row) * HD + col] = (f16)v;
                }
            }
        }
}

// ---------------------------------------------------------------------------
// Decoder stage 1: per-channel upsample 1->4 + LN(4) + scatter-add to mesh.
// Flat: one thread per (element, channel).
// ---------------------------------------------------------------------------
__global__ __launch_bounds__(256)
void dec_up_kernel(const f16* __restrict__ h, const int* __restrict__ conn,
                   const float* __restrict__ uw1, const float* __restrict__ ub1,
                   const float* __restrict__ uw2, const float* __restrict__ ub2,
                   const float* __restrict__ uw3,
                   const float* __restrict__ ulng, const float* __restrict__ ulnb,
                   float* __restrict__ outn) {
    int idx = blockIdx.x * 256 + threadIdx.x;    // 0 .. NTOT*HD-1
    int n = idx >> 7, c = idx & 127;
    int b = n / NE, e = n - b * NE;
    float s = (float)h[idx];
    float u1[4], u2[4], u3[4];
    #pragma unroll
    for (int o = 0; o < 4; ++o) u1[o] = lrelu(s * uw1[c * 4 + o] + ub1[c * 4 + o]);
    #pragma unroll
    for (int o = 0; o < 4; ++o) {
        float a = ub2[c * 4 + o];
        #pragma unroll
        for (int i = 0; i < 4; ++i) a += u1[i] * uw2[c * 16 + i * 4 + o];
        u2[o] = lrelu(a);
    }
    #pragma unroll
    for (int o = 0; o < 4; ++o) {
        float a = 0.f;
        #pragma unroll
        for (int i = 0; i < 4; ++i) a += u2[i] * uw3[c * 16 + i * 4 + o];
        u3[o] = a;
    }
    float m = 0.25f * (u3[0] + u3[1] + u3[2] + u3[3]);
    float var = 0.f;
    #pragma unroll
    for (int o = 0; o < 4; ++o) { float d = u3[o] - m; var += d * d; }
    var *= 0.25f;
    float rs = 1.0f / sqrtf(var + 1e-5f);
    #pragma unroll
    for (int o = 0; o < 4; ++o) {
        float val = (u3[o] - m) * rs * ulng[c * 4 + o] + ulnb[c * 4 + o];
        int nd = conn[e * 4 + o];
        unsafeAtomicAdd(&outn[((size_t)b * NN + nd) * HD + c], val);
    }
}

// ---------------------------------------------------------------------------
// Decoder stage 2: per mesh row H->3->3->3, one wave per row
// ---------------------------------------------------------------------------
__global__ __launch_bounds__(256)
void dec_out_kernel(const float* __restrict__ outn,
                    const float* __restrict__ cw1, const float* __restrict__ cb1,
                    const float* __restrict__ cw2, const float* __restrict__ cb2,
                    const float* __restrict__ cw3,
                    float* __restrict__ o, int nrows) {
    int r = blockIdx.x * 4 + (threadIdx.x >> 6);
    if (r >= nrows) return;
    int lane = threadIdx.x & 63;
    float v1 = outn[(size_t)r * HD + lane];
    float v2 = outn[(size_t)r * HD + 64 + lane];
    float s[3];
    #pragma unroll
    for (int c = 0; c < 3; ++c)
        s[c] = v1 * cw1[lane * 3 + c] + v2 * cw1[(lane + 64) * 3 + c];
    #pragma unroll
    for (int off = 32; off >= 1; off >>= 1) {
        s[0] += __shfl_down(s[0], off);
        s[1] += __shfl_down(s[1], off);
        s[2] += __shfl_down(s[2], off);
    }
    if (lane == 0) {
        float t1[3], t2[3];
        #pragma unroll
        for (int c = 0; c < 3; ++c) t1[c] = lrelu(s[c] + cb1[c]);
        #pragma unroll
        for (int c = 0; c < 3; ++c) {
            float a = cb2[c];
            #pragma unroll
            for (int k = 0; k < 3; ++k) a += t1[k] * cw2[k * 3 + c];
            t2[c] = lrelu(a);
        }
        #pragma unroll
        for (int c = 0; c < 3; ++c) {
            float a = 0.f;
            #pragma unroll
            for (int k = 0; k < 3; ++k) a += t2[k] * cw3[k * 3 + c];
            o[(size_t)r * 3 + c] = a;
        }
    }
}

// ---------------------------------------------------------------------------
extern "C" void kernel_launch(void* const* d_in, const int* in_sizes, int n_in,
                              void* d_out, int out_size, void* d_ws, size_t ws_size,
                              hipStream_t stream) {
    const int* elem_conn = (const int*)d_in[1];
    const int* edge_index = (const int*)d_in[2];
    const int* e_src = edge_index;          // row 0
    const int* e_dst = edge_index + NEDGE;  // row 1
    const float* enc_clnb = (const float*)d_in[9];
    const float* enc_ew1 = (const float*)d_in[10];
    const float* enc_eb1 = (const float*)d_in[11];
    const float* enc_ew2 = (const float*)d_in[12];
    const float* enc_eb2 = (const float*)d_in[13];
    const float* enc_ew3 = (const float*)d_in[14];
    const float* enc_elng = (const float*)d_in[15];
    const float* enc_elnb = (const float*)d_in[16];
    const float* p_ew1 = (const float*)d_in[17];
    const float* p_eb1 = (const float*)d_in[18];
    const float* p_ew2 = (const float*)d_in[19];
    const float* p_eb2 = (const float*)d_in[20];
    const float* p_ew3 = (const float*)d_in[21];
    const float* p_elng = (const float*)d_in[22];
    const float* p_elnb = (const float*)d_in[23];
    const float* p_nw1 = (const float*)d_in[24];
    const float* p_nb1 = (const float*)d_in[25];
    const float* p_nw2 = (const float*)d_in[26];
    const float* p_nb2 = (const float*)d_in[27];
    const float* p_nw3 = (const float*)d_in[28];
    const float* p_nlng = (const float*)d_in[29];
    const float* p_nlnb = (const float*)d_in[30];
    const float* dec_uw1 = (const float*)d_in[31];
    const float* dec_ub1 = (const float*)d_in[32];
    const float* dec_uw2 = (const float*)d_in[33];
    const float* dec_ub2 = (const float*)d_in[34];
    const float* dec_uw3 = (const float*)d_in[35];
    const float* dec_ulng = (const float*)d_in[36];
    const float* dec_ulnb = (const float*)d_in[37];
    const float* dec_cw1 = (const float*)d_in[38];
    const float* dec_cb1 = (const float*)d_in[39];
    const float* dec_cw2 = (const float*)d_in[40];
    const float* dec_cb2 = (const float*)d_in[41];
    const float* dec_cw3 = (const float*)d_in[42];

    // Workspace layout (bytes):
    //   hA16 9.83MB | hB16 9.83MB | wbuf 1.57MB | hv0 512B | aggr16/outn 20.4MB
    char* ws = (char*)d_ws;
    f16* hA16 = (f16*)(ws);
    f16* hB16 = (f16*)(ws + 9830400);
    f16* wbuf = (f16*)(ws + 19660800);
    float* hv0 = (float*)(ws + 21233664);
    f16* aggr16 = (f16*)(ws + 21234176);
    float* outn = (float*)(ws + 21234176);

    enc_const_kernel<<<1, 128, 0, stream>>>(enc_clnb, enc_ew1, enc_eb1, enc_ew2,
                                            enc_eb2, enc_ew3, enc_elng, enc_elnb, hv0);
    init_h16_kernel<<<1200, 256, 0, stream>>>(hA16, hv0, NTOT * HD / 8);
    conv_weights_kernel<<<48, 256, 0, stream>>>(p_ew1, p_ew2, p_ew3,
                                                p_nw1, p_nw2, p_nw3, wbuf);

    for (int d = 0; d < DBLK; ++d) {
        f16* cur = (d & 1) ? hB16 : hA16;
        f16* nxt = (d & 1) ? hA16 : hB16;
        const f16* ws_d = wbuf + (size_t)d * 8 * HD * HD;
        hipMemsetAsync(aggr16, 0, (size_t)NTOT * HD * sizeof(f16), stream);
        gn_mfma<0><<<NEDGE / 64, 256, 0, stream>>>(
            cur, nullptr, e_dst, e_src,
            ws_d + 0 * HD * HD, ws_d + 1 * HD * HD, ws_d + 2 * HD * HD, ws_d + 3 * HD * HD,
            p_eb1 + (size_t)d * HD, p_eb2 + (size_t)d * HD,
            p_elng + (size_t)d * HD, p_elnb + (size_t)d * HD,
            aggr16, nullptr);
        gn_mfma<1><<<NTOT / 64, 256, 0, stream>>>(
            cur, aggr16, nullptr, nullptr,
            ws_d + 4 * HD * HD, ws_d + 5 * HD * HD, ws_d + 6 * HD * HD, ws_d + 7 * HD * HD,
            p_nb1 + (size_t)d * HD, p_nb2 + (size_t)d * HD,
            p_nlng + (size_t)d * HD, p_nlnb + (size_t)d * HD,
            nullptr, nxt);
    }
    // after d=5, result is in hA16
    hipMemsetAsync(outn, 0, (size_t)NMESH * HD * sizeof(float), stream);
    dec_up_kernel<<<NTOT * HD / 256, 256, 0, stream>>>(hA16, elem_conn, dec_uw1, dec_ub1,
                                                       dec_uw2, dec_ub2, dec_uw3,
                                                       dec_ulng, dec_ulnb, outn);
    dec_out_kernel<<<(NMESH + 3) / 4, 256, 0, stream>>>(outn, dec_cw1, dec_cb1,
                                                        dec_cw2, dec_cb2, dec_cw3,
                                                        (float*)d_out, NMESH);
}

// Round 5
// 1016.098 us; speedup vs baseline: 1.2424x; 1.2424x over previous
//
#include <hip/hip_runtime.h>
#include <hip/hip_fp16.h>
#include <math.h>

// Problem constants (from reference)
#define BS    8
#define NE    4800
#define NN    4981
#define CIN   3
#define HD    128      // H
#define DBLK  6        // D processor blocks
#define NEDGE 153600   // BS*EPG
#define NTOT  38400    // BS*NE (graph nodes)
#define NMESH (BS*NN)  // 39848 mesh rows

typedef _Float16 f16;
typedef _Float16 f16x8 __attribute__((ext_vector_type(8)));
typedef float f32x4 __attribute__((ext_vector_type(4)));

__device__ __forceinline__ float lrelu(float x) { return x >= 0.0f ? x : 0.2f * x; }

// ---------------------------------------------------------------------------
// K0: hv0 = ln(mlp(enc_clnb_row, enc_ew1..3), enc_elng, enc_elnb)
// Conv encoder + LayerNorm over size-1 axis collapses exactly to enc_clnb.
// ---------------------------------------------------------------------------
__global__ __launch_bounds__(128)
void enc_const_kernel(const float* __restrict__ clnb,
                      const float* __restrict__ ew1, const float* __restrict__ eb1,
                      const float* __restrict__ ew2, const float* __restrict__ eb2,
                      const float* __restrict__ ew3,
                      const float* __restrict__ g, const float* __restrict__ b,
                      float* __restrict__ hv0) {
    __shared__ float s1[HD], s2[HD], s3[HD];
    int j = threadIdx.x;
    float a = eb1[j];
    for (int c = 0; c < CIN; ++c) a += clnb[c] * ew1[c * HD + j];
    s1[j] = lrelu(a);
    __syncthreads();
    a = eb2[j];
    for (int k = 0; k < HD; ++k) a += s1[k] * ew2[k * HD + j];
    s2[j] = lrelu(a);
    __syncthreads();
    a = 0.0f;
    for (int k = 0; k < HD; ++k) a += s2[k] * ew3[k * HD + j];
    s3[j] = a;
    __syncthreads();
    float m = 0.0f;
    for (int k = 0; k < HD; ++k) m += s3[k];
    m *= (1.0f / HD);
    float v = 0.0f;
    for (int k = 0; k < HD; ++k) { float d = s3[k] - m; v += d * d; }
    v *= (1.0f / HD);
    float rs = 1.0f / sqrtf(v + 1e-5f);
    hv0[j] = (s3[j] - m) * rs * g[j] + b[j];
}

// Broadcast hv0 (fp32) to all NTOT node rows as f16
__global__ __launch_bounds__(256)
void init_h16_kernel(f16* __restrict__ h, const float* __restrict__ hv0, int n8) {
    __shared__ f16 v[HD];
    if (threadIdx.x < HD) v[threadIdx.x] = (f16)hv0[threadIdx.x];
    __syncthreads();
    for (int i = blockIdx.x * blockDim.x + threadIdx.x; i < n8; i += gridDim.x * blockDim.x)
        ((uint4*)h)[i] = ((const uint4*)v)[i & 15];
}

// ---------------------------------------------------------------------------
// Convert + transpose processor weights to f16 Wt[n][k] layout.
// 48 matrices of 128x128: per d: eW1a,eW1b,eW2,eW3,nW1a,nW1b,nW2,nW3
// ---------------------------------------------------------------------------
__global__ __launch_bounds__(256)
void conv_weights_kernel(const float* __restrict__ ew1, const float* __restrict__ ew2,
                         const float* __restrict__ ew3,
                         const float* __restrict__ nw1, const float* __restrict__ nw2,
                         const float* __restrict__ nw3, f16* __restrict__ wbuf) {
    int b = blockIdx.x;        // 0..47
    int d = b >> 3, m = b & 7;
    const float* src;
    switch (m) {
        case 0: src = ew1 + (size_t)d * 2 * HD * HD; break;
        case 1: src = ew1 + (size_t)d * 2 * HD * HD + HD * HD; break;
        case 2: src = ew2 + (size_t)d * HD * HD; break;
        case 3: src = ew3 + (size_t)d * HD * HD; break;
        case 4: src = nw1 + (size_t)d * 2 * HD * HD; break;
        case 5: src = nw1 + (size_t)d * 2 * HD * HD + HD * HD; break;
        case 6: src = nw2 + (size_t)d * HD * HD; break;
        default: src = nw3 + (size_t)d * HD * HD; break;
    }
    f16* out = wbuf + (size_t)b * HD * HD;
    for (int idx = threadIdx.x; idx < HD * HD; idx += 256) {
        int n = idx >> 7, k = idx & 127;
        out[idx] = (f16)src[k * HD + n];   // Wt[n][k] = W[k][n]
    }
}

// ---------------------------------------------------------------------------
// Fused GraphNet MLP tile kernel on MFMA (fp16 in, fp32 accumulate).
// B is staged in LDS, FULL 128x128 MATRIX IN ONE SHOT per GEMM pass:
// 8 independent global_load_dwordx4 per thread -> one L2 round-trip per pass,
// 2 barriers per pass (~10/block vs 64+ in the round-2 chunked version, vs
// L2-latency-serialized B loads in rounds 3/4).
// MODE 0 = edge: A1=h[dest], A2=h[src]; LN out -> packed-f16 atomics to aggr.
// MODE 1 = node: A1=h[row],  A2=aggr16[row]; LN out -> h_out f16.
// Tile 64 rows x 128 cols, 4 waves; wave w: rows (w>>1)*32, cols (w&1)*64,
// 2x4 grid of 16x16x32 MFMA. A[m=lane&15][k=quad*8+j], C/D col=lane&15,
// row=quad*4+reg (guide-verified). LDS 69.5 KB -> 2 blocks/CU.
// ---------------------------------------------------------------------------
__device__ __forceinline__ void stage_w(const f16* __restrict__ Wg, f16 (*Bt)[HD + 8],
                                        int tid) {
    #pragma unroll
    for (int t = 0; t < 8; ++t) {
        int idx = tid + t * 256;            // 0..2047 16B chunks of 128x128 f16
        int r = idx >> 4, c = (idx & 15) * 8;
        *(uint4*)(&Bt[r][c]) = *(const uint4*)(Wg + (size_t)r * HD + c);
    }
}

__device__ __forceinline__ void mfma_pass(const f16 (*A)[HD + 8], const f16 (*Bt)[HD + 8],
                                          int rt_base, int ct_base, int ln, int quad,
                                          f32x4 acc[2][4]) {
    #pragma unroll
    for (int ks = 0; ks < 4; ++ks) {
        int kb = ks * 32 + quad * 8;
        f16x8 a0 = *(const f16x8*)(&A[rt_base + ln][kb]);
        f16x8 a1 = *(const f16x8*)(&A[rt_base + 16 + ln][kb]);
        #pragma unroll
        for (int c = 0; c < 4; ++c) {
            f16x8 b = *(const f16x8*)(&Bt[ct_base + c * 16 + ln][kb]);
            acc[0][c] = __builtin_amdgcn_mfma_f32_16x16x32_f16(a0, b, acc[0][c], 0, 0, 0);
            acc[1][c] = __builtin_amdgcn_mfma_f32_16x16x32_f16(a1, b, acc[1][c], 0, 0, 0);
        }
    }
}

template <int MODE>
__global__ __launch_bounds__(256, 2)
void gn_mfma(const f16* __restrict__ h16, const f16* __restrict__ aggr_in,
             const int* __restrict__ dest, const int* __restrict__ src,
             const f16* __restrict__ W1a, const f16* __restrict__ W1b,
             const f16* __restrict__ W2, const f16* __restrict__ W3,
             const float* __restrict__ b1, const float* __restrict__ b2,
             const float* __restrict__ g, const float* __restrict__ bln,
             f16* __restrict__ aggr_out, f16* __restrict__ h_out) {
    __shared__ __align__(16) f16 As1[64][HD + 8];
    __shared__ __align__(16) f16 As2[64][HD + 8];
    __shared__ __align__(16) f16 Bt[HD][HD + 8];
    __shared__ float red[64][2][2];
    __shared__ int dS[64], sS[64];

    const int tid = threadIdx.x;
    const int base = blockIdx.x * 64;
    const int wave = tid >> 6;
    const int lane = tid & 63;
    const int ln = lane & 15;
    const int quad = lane >> 4;
    const int rt_base = (wave >> 1) * 32;
    const int ct_base = (wave & 1) * 64;
    const int half = wave & 1;

    if (MODE == 0) {
        if (tid < 64) dS[tid] = dest[base + tid];
        else if (tid < 128) sS[tid - 64] = src[base + tid - 64];
        __syncthreads();
    }

    // ---- Stage A tiles + W1a (concurrently; both visible after one sync)
    #pragma unroll
    for (int t = 0; t < 4; ++t) {
        int idx = tid + t * 256;            // 0..1023
        int r = idx >> 4, c = (idx & 15) * 8;
        if (MODE == 0) {
            *(uint4*)(&As1[r][c]) = *(const uint4*)(h16 + (size_t)dS[r] * HD + c);
            *(uint4*)(&As2[r][c]) = *(const uint4*)(h16 + (size_t)sS[r] * HD + c);
        } else {
            *(uint4*)(&As1[r][c]) = *(const uint4*)(h16 + (size_t)(base + r) * HD + c);
            *(uint4*)(&As2[r][c]) = *(const uint4*)(aggr_in + (size_t)(base + r) * HD + c);
        }
    }
    stage_w(W1a, Bt, tid);
    __syncthreads();

    f32x4 acc[2][4];

    // ---- Layer 1: K=256 over [As1 | As2], bias b1, lrelu
    #pragma unroll
    for (int c = 0; c < 4; ++c) {
        float bj = b1[ct_base + c * 16 + ln];
        f32x4 bb = {bj, bj, bj, bj};
        acc[0][c] = bb; acc[1][c] = bb;
    }
    mfma_pass(As1, Bt, rt_base, ct_base, ln, quad, acc);
    __syncthreads();                    // Bt readers done
    stage_w(W1b, Bt, tid);
    __syncthreads();                    // W1b visible
    mfma_pass(As2, Bt, rt_base, ct_base, ln, quad, acc);
    __syncthreads();                    // Bt + As1 readers done
    stage_w(W2, Bt, tid);
    #pragma unroll
    for (int i = 0; i < 2; ++i)
        #pragma unroll
        for (int c = 0; c < 4; ++c)
            #pragma unroll
            for (int r = 0; r < 4; ++r)
                As1[rt_base + i * 16 + quad * 4 + r][ct_base + c * 16 + ln] =
                    (f16)lrelu(acc[i][c][r]);
    __syncthreads();                    // W2 + act1 visible

    // ---- Layer 2: K=128 over As1(act1), bias b2, lrelu
    #pragma unroll
    for (int c = 0; c < 4; ++c) {
        float bj = b2[ct_base + c * 16 + ln];
        f32x4 bb = {bj, bj, bj, bj};
        acc[0][c] = bb; acc[1][c] = bb;
    }
    mfma_pass(As1, Bt, rt_base, ct_base, ln, quad, acc);
    __syncthreads();                    // Bt + As2 readers done
    stage_w(W3, Bt, tid);
    #pragma unroll
    for (int i = 0; i < 2; ++i)
        #pragma unroll
        for (int c = 0; c < 4; ++c)
            #pragma unroll
            for (int r = 0; r < 4; ++r)
                As2[rt_base + i * 16 + quad * 4 + r][ct_base + c * 16 + ln] =
                    (f16)lrelu(acc[i][c][r]);
    __syncthreads();                    // W3 + act2 visible

    // ---- Layer 3: K=128 over As2(act2), no bias/activation
    #pragma unroll
    for (int c = 0; c < 4; ++c) {
        f32x4 z = {0.f, 0.f, 0.f, 0.f};
        acc[0][c] = z; acc[1][c] = z;
    }
    mfma_pass(As2, Bt, rt_base, ct_base, ln, quad, acc);

    // ---- LayerNorm stats: quad-level shfl reduce (xor 1,2,4,8 stay in-quad),
    // combine the two column-halves through LDS
    #pragma unroll
    for (int i = 0; i < 2; ++i)
        #pragma unroll
        for (int r = 0; r < 4; ++r) {
            float s = acc[i][0][r] + acc[i][1][r] + acc[i][2][r] + acc[i][3][r];
            float q = acc[i][0][r] * acc[i][0][r] + acc[i][1][r] * acc[i][1][r] +
                      acc[i][2][r] * acc[i][2][r] + acc[i][3][r] * acc[i][3][r];
            s += __shfl_xor(s, 1); q += __shfl_xor(q, 1);
            s += __shfl_xor(s, 2); q += __shfl_xor(q, 2);
            s += __shfl_xor(s, 4); q += __shfl_xor(q, 4);
            s += __shfl_xor(s, 8); q += __shfl_xor(q, 8);
            if (ln == 0) {
                int row = rt_base + i * 16 + quad * 4 + r;
                red[row][half][0] = s;
                red[row][half][1] = q;
            }
        }
    __syncthreads();

    // ---- Epilogue: LN scale + packed-f16 atomics (edge) or f16 store (node)
    float gv[4], bv[4];
    #pragma unroll
    for (int c = 0; c < 4; ++c) {
        int col = ct_base + c * 16 + ln;
        gv[c] = g[col]; bv[c] = bln[col];
    }
    #pragma unroll
    for (int i = 0; i < 2; ++i)
        #pragma unroll
        for (int r = 0; r < 4; ++r) {
            int row = rt_base + i * 16 + quad * 4 + r;
            float s = red[row][0][0] + red[row][1][0];
            float q = red[row][0][1] + red[row][1][1];
            float m = s * (1.0f / HD);
            float var = q * (1.0f / HD) - m * m;
            float rs = 1.0f / sqrtf(var + 1e-5f);
            #pragma unroll
            for (int c = 0; c < 4; ++c) {
                int col = ct_base + c * 16 + ln;
                float v = (acc[i][c][r] - m) * rs * gv[c] + bv[c];
                if (MODE == 0) {
                    float pv = __shfl_xor(v, 1);   // partner col (ln^1)
                    if (!(ln & 1)) {
                        __half2 h2 = __floats2half2_rn(v, pv);
                        unsafeAtomicAdd((__half2*)(aggr_out + (size_t)dS[row] * HD + col),
                                        h2);
                    }
                } else {
                    h_out[(size_t)(base + row) * HD + col] = (f16)v;
                }
            }
        }
}

// ---------------------------------------------------------------------------
// Decoder stage 1: per-channel upsample 1->4 + LN(4) + scatter-add to mesh.
// Flat: one thread per (element, channel).
// ---------------------------------------------------------------------------
__global__ __launch_bounds__(256)
void dec_up_kernel(const f16* __restrict__ h, const int* __restrict__ conn,
                   const float* __restrict__ uw1, const float* __restrict__ ub1,
                   const float* __restrict__ uw2, const float* __restrict__ ub2,
                   const float* __restrict__ uw3,
                   const float* __restrict__ ulng, const float* __restrict__ ulnb,
                   float* __restrict__ outn) {
    int idx = blockIdx.x * 256 + threadIdx.x;    // 0 .. NTOT*HD-1
    int n = idx >> 7, c = idx & 127;
    int b = n / NE, e = n - b * NE;
    float s = (float)h[idx];
    float u1[4], u2[4], u3[4];
    #pragma unroll
    for (int o = 0; o < 4; ++o) u1[o] = lrelu(s * uw1[c * 4 + o] + ub1[c * 4 + o]);
    #pragma unroll
    for (int o = 0; o < 4; ++o) {
        float a = ub2[c * 4 + o];
        #pragma unroll
        for (int i = 0; i < 4; ++i) a += u1[i] * uw2[c * 16 + i * 4 + o];
        u2[o] = lrelu(a);
    }
    #pragma unroll
    for (int o = 0; o < 4; ++o) {
        float a = 0.f;
        #pragma unroll
        for (int i = 0; i < 4; ++i) a += u2[i] * uw3[c * 16 + i * 4 + o];
        u3[o] = a;
    }
    float m = 0.25f * (u3[0] + u3[1] + u3[2] + u3[3]);
    float var = 0.f;
    #pragma unroll
    for (int o = 0; o < 4; ++o) { float d = u3[o] - m; var += d * d; }
    var *= 0.25f;
    float rs = 1.0f / sqrtf(var + 1e-5f);
    #pragma unroll
    for (int o = 0; o < 4; ++o) {
        float val = (u3[o] - m) * rs * ulng[c * 4 + o] + ulnb[c * 4 + o];
        int nd = conn[e * 4 + o];
        unsafeAtomicAdd(&outn[((size_t)b * NN + nd) * HD + c], val);
    }
}

// ---------------------------------------------------------------------------
// Decoder stage 2: per mesh row H->3->3->3, one wave per row
// ---------------------------------------------------------------------------
__global__ __launch_bounds__(256)
void dec_out_kernel(const float* __restrict__ outn,
                    const float* __restrict__ cw1, const float* __restrict__ cb1,
                    const float* __restrict__ cw2, const float* __restrict__ cb2,
                    const float* __restrict__ cw3,
                    float* __restrict__ o, int nrows) {
    int r = blockIdx.x * 4 + (threadIdx.x >> 6);
    if (r >= nrows) return;
    int lane = threadIdx.x & 63;
    float v1 = outn[(size_t)r * HD + lane];
    float v2 = outn[(size_t)r * HD + 64 + lane];
    float s[3];
    #pragma unroll
    for (int c = 0; c < 3; ++c)
        s[c] = v1 * cw1[lane * 3 + c] + v2 * cw1[(lane + 64) * 3 + c];
    #pragma unroll
    for (int off = 32; off >= 1; off >>= 1) {
        s[0] += __shfl_down(s[0], off);
        s[1] += __shfl_down(s[1], off);
        s[2] += __shfl_down(s[2], off);
    }
    if (lane == 0) {
        float t1[3], t2[3];
        #pragma unroll
        for (int c = 0; c < 3; ++c) t1[c] = lrelu(s[c] + cb1[c]);
        #pragma unroll
        for (int c = 0; c < 3; ++c) {
            float a = cb2[c];
            #pragma unroll
            for (int k = 0; k < 3; ++k) a += t1[k] * cw2[k * 3 + c];
            t2[c] = lrelu(a);
        }
        #pragma unroll
        for (int c = 0; c < 3; ++c) {
            float a = 0.f;
            #pragma unroll
            for (int k = 0; k < 3; ++k) a += t2[k] * cw3[k * 3 + c];
            o[(size_t)r * 3 + c] = a;
        }
    }
}

// ---------------------------------------------------------------------------
extern "C" void kernel_launch(void* const* d_in, const int* in_sizes, int n_in,
                              void* d_out, int out_size, void* d_ws, size_t ws_size,
                              hipStream_t stream) {
    const int* elem_conn = (const int*)d_in[1];
    const int* edge_index = (const int*)d_in[2];
    const int* e_src = edge_index;          // row 0
    const int* e_dst = edge_index + NEDGE;  // row 1
    const float* enc_clnb = (const float*)d_in[9];
    const float* enc_ew1 = (const float*)d_in[10];
    const float* enc_eb1 = (const float*)d_in[11];
    const float* enc_ew2 = (const float*)d_in[12];
    const float* enc_eb2 = (const float*)d_in[13];
    const float* enc_ew3 = (const float*)d_in[14];
    const float* enc_elng = (const float*)d_in[15];
    const float* enc_elnb = (const float*)d_in[16];
    const float* p_ew1 = (const float*)d_in[17];
    const float* p_eb1 = (const float*)d_in[18];
    const float* p_ew2 = (const float*)d_in[19];
    const float* p_eb2 = (const float*)d_in[20];
    const float* p_ew3 = (const float*)d_in[21];
    const float* p_elng = (const float*)d_in[22];
    const float* p_elnb = (const float*)d_in[23];
    const float* p_nw1 = (const float*)d_in[24];
    const float* p_nb1 = (const float*)d_in[25];
    const float* p_nw2 = (const float*)d_in[26];
    const float* p_nb2 = (const float*)d_in[27];
    const float* p_nw3 = (const float*)d_in[28];
    const float* p_nlng = (const float*)d_in[29];
    const float* p_nlnb = (const float*)d_in[30];
    const float* dec_uw1 = (const float*)d_in[31];
    const float* dec_ub1 = (const float*)d_in[32];
    const float* dec_uw2 = (const float*)d_in[33];
    const float* dec_ub2 = (const float*)d_in[34];
    const float* dec_uw3 = (const float*)d_in[35];
    const float* dec_ulng = (const float*)d_in[36];
    const float* dec_ulnb = (const float*)d_in[37];
    const float* dec_cw1 = (const float*)d_in[38];
    const float* dec_cb1 = (const float*)d_in[39];
    const float* dec_cw2 = (const float*)d_in[40];
    const float* dec_cb2 = (const float*)d_in[41];
    const float* dec_cw3 = (const float*)d_in[42];

    // Workspace layout (bytes):
    //   hA16 9.83MB | hB16 9.83MB | wbuf 1.57MB | hv0 512B | aggr16/outn 20.4MB
    char* ws = (char*)d_ws;
    f16* hA16 = (f16*)(ws);
    f16* hB16 = (f16*)(ws + 9830400);
    f16* wbuf = (f16*)(ws + 19660800);
    float* hv0 = (float*)(ws + 21233664);
    f16* aggr16 = (f16*)(ws + 21234176);
    float* outn = (float*)(ws + 21234176);

    enc_const_kernel<<<1, 128, 0, stream>>>(enc_clnb, enc_ew1, enc_eb1, enc_ew2,
                                            enc_eb2, enc_ew3, enc_elng, enc_elnb, hv0);
    init_h16_kernel<<<1200, 256, 0, stream>>>(hA16, hv0, NTOT * HD / 8);
    conv_weights_kernel<<<48, 256, 0, stream>>>(p_ew1, p_ew2, p_ew3,
                                                p_nw1, p_nw2, p_nw3, wbuf);

    for (int d = 0; d < DBLK; ++d) {
        f16* cur = (d & 1) ? hB16 : hA16;
        f16* nxt = (d & 1) ? hA16 : hB16;
        const f16* ws_d = wbuf + (size_t)d * 8 * HD * HD;
        hipMemsetAsync(aggr16, 0, (size_t)NTOT * HD * sizeof(f16), stream);
        gn_mfma<0><<<NEDGE / 64, 256, 0, stream>>>(
            cur, nullptr, e_dst, e_src,
            ws_d + 0 * HD * HD, ws_d + 1 * HD * HD, ws_d + 2 * HD * HD, ws_d + 3 * HD * HD,
            p_eb1 + (size_t)d * HD, p_eb2 + (size_t)d * HD,
            p_elng + (size_t)d * HD, p_elnb + (size_t)d * HD,
            aggr16, nullptr);
        gn_mfma<1><<<NTOT / 64, 256, 0, stream>>>(
            cur, aggr16, nullptr, nullptr,
            ws_d + 4 * HD * HD, ws_d + 5 * HD * HD, ws_d + 6 * HD * HD, ws_d + 7 * HD * HD,
            p_nb1 + (size_t)d * HD, p_nb2 + (size_t)d * HD,
            p_nlng + (size_t)d * HD, p_nlnb + (size_t)d * HD,
            nullptr, nxt);
    }
    // after d=5, result is in hA16
    hipMemsetAsync(outn, 0, (size_t)NMESH * HD * sizeof(float), stream);
    dec_up_kernel<<<NTOT * HD / 256, 256, 0, stream>>>(hA16, elem_conn, dec_uw1, dec_ub1,
                                                       dec_uw2, dec_ub2, dec_uw3,
                                                       dec_ulng, dec_ulnb, outn);
    dec_out_kernel<<<(NMESH + 3) / 4, 256, 0, stream>>>(outn, dec_cw1, dec_cb1,
                                                        dec_cw2, dec_cb2, dec_cw3,
                                                        (float*)d_out, NMESH);
}

// Round 6
// 1002.833 us; speedup vs baseline: 1.2588x; 1.0132x over previous
//
#include <hip/hip_runtime.h>
#include <hip/hip_fp16.h>
#include <math.h>

// Problem constants (from reference)
#define BS    8
#define NE    4800
#define NN    4981
#define CIN   3
#define HD    128      // H
#define DBLK  6        // D processor blocks
#define NEDGE 153600   // BS*EPG
#define NTOT  38400    // BS*NE (graph nodes)
#define NMESH (BS*NN)  // 39848 mesh rows

typedef _Float16 f16;
typedef _Float16 f16x8 __attribute__((ext_vector_type(8)));
typedef float f32x4 __attribute__((ext_vector_type(4)));

__device__ __forceinline__ float lrelu(float x) { return x >= 0.0f ? x : 0.2f * x; }

// ---------------------------------------------------------------------------
// K0: hv0 = ln(mlp(enc_clnb_row, enc_ew1..3), enc_elng, enc_elnb)
// Conv encoder + LayerNorm over size-1 axis collapses exactly to enc_clnb.
// ---------------------------------------------------------------------------
__global__ __launch_bounds__(128)
void enc_const_kernel(const float* __restrict__ clnb,
                      const float* __restrict__ ew1, const float* __restrict__ eb1,
                      const float* __restrict__ ew2, const float* __restrict__ eb2,
                      const float* __restrict__ ew3,
                      const float* __restrict__ g, const float* __restrict__ b,
                      float* __restrict__ hv0) {
    __shared__ float s1[HD], s2[HD], s3[HD];
    int j = threadIdx.x;
    float a = eb1[j];
    for (int c = 0; c < CIN; ++c) a += clnb[c] * ew1[c * HD + j];
    s1[j] = lrelu(a);
    __syncthreads();
    a = eb2[j];
    for (int k = 0; k < HD; ++k) a += s1[k] * ew2[k * HD + j];
    s2[j] = lrelu(a);
    __syncthreads();
    a = 0.0f;
    for (int k = 0; k < HD; ++k) a += s2[k] * ew3[k * HD + j];
    s3[j] = a;
    __syncthreads();
    float m = 0.0f;
    for (int k = 0; k < HD; ++k) m += s3[k];
    m *= (1.0f / HD);
    float v = 0.0f;
    for (int k = 0; k < HD; ++k) { float d = s3[k] - m; v += d * d; }
    v *= (1.0f / HD);
    float rs = 1.0f / sqrtf(v + 1e-5f);
    hv0[j] = (s3[j] - m) * rs * g[j] + b[j];
}

// Broadcast hv0 (fp32) to all NTOT node rows as f16
__global__ __launch_bounds__(256)
void init_h16_kernel(f16* __restrict__ h, const float* __restrict__ hv0, int n8) {
    __shared__ f16 v[HD];
    if (threadIdx.x < HD) v[threadIdx.x] = (f16)hv0[threadIdx.x];
    __syncthreads();
    for (int i = blockIdx.x * blockDim.x + threadIdx.x; i < n8; i += gridDim.x * blockDim.x)
        ((uint4*)h)[i] = ((const uint4*)v)[i & 15];
}

// ---------------------------------------------------------------------------
// Convert + transpose processor weights to f16 Wt[n][k] layout.
// 48 matrices of 128x128: per d: eW1a,eW1b,eW2,eW3,nW1a,nW1b,nW2,nW3
// ---------------------------------------------------------------------------
__global__ __launch_bounds__(256)
void conv_weights_kernel(const float* __restrict__ ew1, const float* __restrict__ ew2,
                         const float* __restrict__ ew3,
                         const float* __restrict__ nw1, const float* __restrict__ nw2,
                         const float* __restrict__ nw3, f16* __restrict__ wbuf) {
    int b = blockIdx.x;        // 0..47
    int d = b >> 3, m = b & 7;
    const float* src;
    switch (m) {
        case 0: src = ew1 + (size_t)d * 2 * HD * HD; break;
        case 1: src = ew1 + (size_t)d * 2 * HD * HD + HD * HD; break;
        case 2: src = ew2 + (size_t)d * HD * HD; break;
        case 3: src = ew3 + (size_t)d * HD * HD; break;
        case 4: src = nw1 + (size_t)d * 2 * HD * HD; break;
        case 5: src = nw1 + (size_t)d * 2 * HD * HD + HD * HD; break;
        case 6: src = nw2 + (size_t)d * HD * HD; break;
        default: src = nw3 + (size_t)d * HD * HD; break;
    }
    f16* out = wbuf + (size_t)b * HD * HD;
    for (int idx = threadIdx.x; idx < HD * HD; idx += 256) {
        int n = idx >> 7, k = idx & 127;
        out[idx] = (f16)src[k * HD + n];   // Wt[n][k] = W[k][n]
    }
}

// ---------------------------------------------------------------------------
// Shared GEMM helpers. Tile 64 rows x 128 cols, 4 waves; wave w: rows
// (w>>1)*32, cols (w&1)*64, 2x4 grid of 16x16x32 MFMA.
// A[m=lane&15][k=quad*8+j], C/D col=lane&15, row=quad*4+reg (guide-verified).
// ---------------------------------------------------------------------------
__device__ __forceinline__ void stage_w(const f16* __restrict__ Wg, f16 (*Bt)[HD + 8],
                                        int tid) {
    #pragma unroll
    for (int t = 0; t < 8; ++t) {
        int idx = tid + t * 256;            // 0..2047 16B chunks of 128x128 f16
        int r = idx >> 4, c = (idx & 15) * 8;
        *(uint4*)(&Bt[r][c]) = *(const uint4*)(Wg + (size_t)r * HD + c);
    }
}

__device__ __forceinline__ void mfma_pass(const f16 (*A)[HD + 8], const f16 (*Bt)[HD + 8],
                                          int rt_base, int ct_base, int ln, int quad,
                                          f32x4 acc[2][4]) {
    #pragma unroll
    for (int ks = 0; ks < 4; ++ks) {
        int kb = ks * 32 + quad * 8;
        f16x8 a0 = *(const f16x8*)(&A[rt_base + ln][kb]);
        f16x8 a1 = *(const f16x8*)(&A[rt_base + 16 + ln][kb]);
        #pragma unroll
        for (int c = 0; c < 4; ++c) {
            f16x8 b = *(const f16x8*)(&Bt[ct_base + c * 16 + ln][kb]);
            acc[0][c] = __builtin_amdgcn_mfma_f32_16x16x32_f16(a0, b, acc[0][c], 0, 0, 0);
            acc[1][c] = __builtin_amdgcn_mfma_f32_16x16x32_f16(a1, b, acc[1][c], 0, 0, 0);
        }
    }
}

// ---------------------------------------------------------------------------
// Per-node precompute: P1 = h@eW1a, P2 = h@eW1b (no bias), f16 out.
// Plain dense GEMM over contiguous rows; LDS 52.2 KB -> 3 blocks/CU.
// ---------------------------------------------------------------------------
__global__ __launch_bounds__(256, 3)
void p_pre_kernel(const f16* __restrict__ h16,
                  const f16* __restrict__ W1a, const f16* __restrict__ W1b,
                  f16* __restrict__ P1, f16* __restrict__ P2) {
    __shared__ __align__(16) f16 As[64][HD + 8];
    __shared__ __align__(16) f16 Bt[HD][HD + 8];
    const int tid = threadIdx.x;
    const int base = blockIdx.x * 64;
    const int wave = tid >> 6, lane = tid & 63;
    const int ln = lane & 15, quad = lane >> 4;
    const int rt_base = (wave >> 1) * 32;
    const int ct_base = (wave & 1) * 64;

    #pragma unroll
    for (int t = 0; t < 2; ++t) {
        int idx = tid + t * 256;            // 0..511: 64 rows x 8 chunks? no: 16 chunks
        int r = idx >> 4, c = (idx & 15) * 8;
        *(uint4*)(&As[r][c]) = *(const uint4*)(h16 + (size_t)(base + r) * HD + c);
        int idx2 = idx + 512;
        int r2 = idx2 >> 4, c2 = (idx2 & 15) * 8;
        *(uint4*)(&As[r2][c2]) = *(const uint4*)(h16 + (size_t)(base + r2) * HD + c2);
    }
    stage_w(W1a, Bt, tid);
    __syncthreads();

    f32x4 acc[2][4];
    #pragma unroll
    for (int c = 0; c < 4; ++c) { f32x4 z = {0,0,0,0}; acc[0][c] = z; acc[1][c] = z; }
    mfma_pass(As, Bt, rt_base, ct_base, ln, quad, acc);
    #pragma unroll
    for (int i = 0; i < 2; ++i)
        #pragma unroll
        for (int c = 0; c < 4; ++c)
            #pragma unroll
            for (int r = 0; r < 4; ++r)
                P1[(size_t)(base + rt_base + i * 16 + quad * 4 + r) * HD +
                   ct_base + c * 16 + ln] = (f16)acc[i][c][r];
    __syncthreads();                        // Bt readers done
    stage_w(W1b, Bt, tid);
    __syncthreads();
    #pragma unroll
    for (int c = 0; c < 4; ++c) { f32x4 z = {0,0,0,0}; acc[0][c] = z; acc[1][c] = z; }
    mfma_pass(As, Bt, rt_base, ct_base, ln, quad, acc);
    #pragma unroll
    for (int i = 0; i < 2; ++i)
        #pragma unroll
        for (int c = 0; c < 4; ++c)
            #pragma unroll
            for (int r = 0; r < 4; ++r)
                P2[(size_t)(base + rt_base + i * 16 + quad * 4 + r) * HD +
                   ct_base + c * 16 + ln] = (f16)acc[i][c][r];
}

// ---------------------------------------------------------------------------
// Edge kernel: act1 = lrelu(P1[dest]+P2[src]+b1)  (algebraic L1 split — no
// L1 GEMM per edge), then 2 MFMA passes (W2, W3), LN, fp32 atomic scatter.
// LDS 53.8 KB -> 3 blocks/CU (12 waves of outstanding random gathers).
// ---------------------------------------------------------------------------
__global__ __launch_bounds__(256, 3)
void gn_edge(const f16* __restrict__ P1, const f16* __restrict__ P2,
             const int* __restrict__ dest, const int* __restrict__ src,
             const f16* __restrict__ W2, const f16* __restrict__ W3,
             const float* __restrict__ b1, const float* __restrict__ b2,
             const float* __restrict__ g, const float* __restrict__ bln,
             float* __restrict__ aggr_out) {
    __shared__ __align__(16) f16 As[64][HD + 8];
    __shared__ __align__(16) f16 Bt[HD][HD + 8];
    __shared__ float red[64][2][2];
    __shared__ int dS[64], sS[64];

    const int tid = threadIdx.x;
    const int base = blockIdx.x * 64;
    const int wave = tid >> 6, lane = tid & 63;
    const int ln = lane & 15, quad = lane >> 4;
    const int rt_base = (wave >> 1) * 32;
    const int ct_base = (wave & 1) * 64;
    const int half = wave & 1;

    if (tid < 64) dS[tid] = dest[base + tid];
    else if (tid < 128) sS[tid - 64] = src[base + tid - 64];
    __syncthreads();

    // ---- Gather P1[d]+P2[s], add bias, lrelu -> act1 in As; stage W2 to Bt
    stage_w(W2, Bt, tid);
    #pragma unroll
    for (int t = 0; t < 4; ++t) {
        int idx = tid + t * 256;            // 0..1023
        int r = idx >> 4, c = (idx & 15) * 8;
        f16x8 p1 = *(const f16x8*)(P1 + (size_t)dS[r] * HD + c);
        f16x8 p2 = *(const f16x8*)(P2 + (size_t)sS[r] * HD + c);
        float4 ba = *(const float4*)(b1 + c);
        float4 bb = *(const float4*)(b1 + c + 4);
        f16x8 o;
        o[0] = (f16)lrelu((float)p1[0] + (float)p2[0] + ba.x);
        o[1] = (f16)lrelu((float)p1[1] + (float)p2[1] + ba.y);
        o[2] = (f16)lrelu((float)p1[2] + (float)p2[2] + ba.z);
        o[3] = (f16)lrelu((float)p1[3] + (float)p2[3] + ba.w);
        o[4] = (f16)lrelu((float)p1[4] + (float)p2[4] + bb.x);
        o[5] = (f16)lrelu((float)p1[5] + (float)p2[5] + bb.y);
        o[6] = (f16)lrelu((float)p1[6] + (float)p2[6] + bb.z);
        o[7] = (f16)lrelu((float)p1[7] + (float)p2[7] + bb.w);
        *(f16x8*)(&As[r][c]) = o;
    }
    __syncthreads();

    f32x4 acc[2][4];

    // ---- Layer 2: K=128 over act1, bias b2, lrelu
    #pragma unroll
    for (int c = 0; c < 4; ++c) {
        float bj = b2[ct_base + c * 16 + ln];
        f32x4 bb = {bj, bj, bj, bj};
        acc[0][c] = bb; acc[1][c] = bb;
    }
    mfma_pass(As, Bt, rt_base, ct_base, ln, quad, acc);
    __syncthreads();                        // As + Bt readers done
    stage_w(W3, Bt, tid);
    #pragma unroll
    for (int i = 0; i < 2; ++i)
        #pragma unroll
        for (int c = 0; c < 4; ++c)
            #pragma unroll
            for (int r = 0; r < 4; ++r)
                As[rt_base + i * 16 + quad * 4 + r][ct_base + c * 16 + ln] =
                    (f16)lrelu(acc[i][c][r]);
    __syncthreads();                        // W3 + act2 visible

    // ---- Layer 3: K=128 over act2
    #pragma unroll
    for (int c = 0; c < 4; ++c) { f32x4 z = {0,0,0,0}; acc[0][c] = z; acc[1][c] = z; }
    mfma_pass(As, Bt, rt_base, ct_base, ln, quad, acc);

    // ---- LayerNorm stats: quad shfl reduce, halves combined via LDS
    #pragma unroll
    for (int i = 0; i < 2; ++i)
        #pragma unroll
        for (int r = 0; r < 4; ++r) {
            float s = acc[i][0][r] + acc[i][1][r] + acc[i][2][r] + acc[i][3][r];
            float q = acc[i][0][r] * acc[i][0][r] + acc[i][1][r] * acc[i][1][r] +
                      acc[i][2][r] * acc[i][2][r] + acc[i][3][r] * acc[i][3][r];
            s += __shfl_xor(s, 1); q += __shfl_xor(q, 1);
            s += __shfl_xor(s, 2); q += __shfl_xor(q, 2);
            s += __shfl_xor(s, 4); q += __shfl_xor(q, 4);
            s += __shfl_xor(s, 8); q += __shfl_xor(q, 8);
            if (ln == 0) {
                int row = rt_base + i * 16 + quad * 4 + r;
                red[row][half][0] = s;
                red[row][half][1] = q;
            }
        }
    __syncthreads();

    // ---- Epilogue: LN scale + fp32 atomic scatter (native global fadd)
    float gv[4], bv[4];
    #pragma unroll
    for (int c = 0; c < 4; ++c) {
        int col = ct_base + c * 16 + ln;
        gv[c] = g[col]; bv[c] = bln[col];
    }
    #pragma unroll
    for (int i = 0; i < 2; ++i)
        #pragma unroll
        for (int r = 0; r < 4; ++r) {
            int row = rt_base + i * 16 + quad * 4 + r;
            float s = red[row][0][0] + red[row][1][0];
            float q = red[row][0][1] + red[row][1][1];
            float m = s * (1.0f / HD);
            float var = q * (1.0f / HD) - m * m;
            float rs = 1.0f / sqrtf(var + 1e-5f);
            float* p = aggr_out + (size_t)dS[row] * HD;
            #pragma unroll
            for (int c = 0; c < 4; ++c) {
                int col = ct_base + c * 16 + ln;
                float v = (acc[i][c][r] - m) * rs * gv[c] + bv[c];
                atomicAdd(p + col, v);
            }
        }
}

// ---------------------------------------------------------------------------
// Node kernel: A1=h[row] (f16), A2=aggr[row] (fp32->f16); 4 MFMA passes
// (nW1a, nW1b, nW2, nW3), LN, writes h IN-PLACE (block reads exactly the rows
// it writes; reads complete before epilogue). LDS 70.7 KB -> 2 blocks/CU.
// ---------------------------------------------------------------------------
__global__ __launch_bounds__(256, 2)
void gn_node(f16* __restrict__ h16, const float* __restrict__ aggr_in,
             const f16* __restrict__ W1a, const f16* __restrict__ W1b,
             const f16* __restrict__ W2, const f16* __restrict__ W3,
             const float* __restrict__ b1, const float* __restrict__ b2,
             const float* __restrict__ g, const float* __restrict__ bln) {
    __shared__ __align__(16) f16 As1[64][HD + 8];
    __shared__ __align__(16) f16 As2[64][HD + 8];
    __shared__ __align__(16) f16 Bt[HD][HD + 8];
    __shared__ float red[64][2][2];

    const int tid = threadIdx.x;
    const int base = blockIdx.x * 64;
    const int wave = tid >> 6, lane = tid & 63;
    const int ln = lane & 15, quad = lane >> 4;
    const int rt_base = (wave >> 1) * 32;
    const int ct_base = (wave & 1) * 64;
    const int half = wave & 1;

    #pragma unroll
    for (int t = 0; t < 4; ++t) {
        int idx = tid + t * 256;            // 0..1023
        int r = idx >> 4, c = (idx & 15) * 8;
        *(uint4*)(&As1[r][c]) = *(const uint4*)(h16 + (size_t)(base + r) * HD + c);
        const float* p = aggr_in + (size_t)(base + r) * HD + c;
        float4 u = *(const float4*)p;
        float4 v = *(const float4*)(p + 4);
        f16x8 hv;
        hv[0] = (f16)u.x; hv[1] = (f16)u.y; hv[2] = (f16)u.z; hv[3] = (f16)u.w;
        hv[4] = (f16)v.x; hv[5] = (f16)v.y; hv[6] = (f16)v.z; hv[7] = (f16)v.w;
        *(f16x8*)(&As2[r][c]) = hv;
    }
    stage_w(W1a, Bt, tid);
    __syncthreads();

    f32x4 acc[2][4];
    #pragma unroll
    for (int c = 0; c < 4; ++c) {
        float bj = b1[ct_base + c * 16 + ln];
        f32x4 bb = {bj, bj, bj, bj};
        acc[0][c] = bb; acc[1][c] = bb;
    }
    mfma_pass(As1, Bt, rt_base, ct_base, ln, quad, acc);
    __syncthreads();
    stage_w(W1b, Bt, tid);
    __syncthreads();
    mfma_pass(As2, Bt, rt_base, ct_base, ln, quad, acc);
    __syncthreads();
    stage_w(W2, Bt, tid);
    #pragma unroll
    for (int i = 0; i < 2; ++i)
        #pragma unroll
        for (int c = 0; c < 4; ++c)
            #pragma unroll
            for (int r = 0; r < 4; ++r)
                As1[rt_base + i * 16 + quad * 4 + r][ct_base + c * 16 + ln] =
                    (f16)lrelu(acc[i][c][r]);
    __syncthreads();

    #pragma unroll
    for (int c = 0; c < 4; ++c) {
        float bj = b2[ct_base + c * 16 + ln];
        f32x4 bb = {bj, bj, bj, bj};
        acc[0][c] = bb; acc[1][c] = bb;
    }
    mfma_pass(As1, Bt, rt_base, ct_base, ln, quad, acc);
    __syncthreads();
    stage_w(W3, Bt, tid);
    #pragma unroll
    for (int i = 0; i < 2; ++i)
        #pragma unroll
        for (int c = 0; c < 4; ++c)
            #pragma unroll
            for (int r = 0; r < 4; ++r)
                As2[rt_base + i * 16 + quad * 4 + r][ct_base + c * 16 + ln] =
                    (f16)lrelu(acc[i][c][r]);
    __syncthreads();

    #pragma unroll
    for (int c = 0; c < 4; ++c) { f32x4 z = {0,0,0,0}; acc[0][c] = z; acc[1][c] = z; }
    mfma_pass(As2, Bt, rt_base, ct_base, ln, quad, acc);

    #pragma unroll
    for (int i = 0; i < 2; ++i)
        #pragma unroll
        for (int r = 0; r < 4; ++r) {
            float s = acc[i][0][r] + acc[i][1][r] + acc[i][2][r] + acc[i][3][r];
            float q = acc[i][0][r] * acc[i][0][r] + acc[i][1][r] * acc[i][1][r] +
                      acc[i][2][r] * acc[i][2][r] + acc[i][3][r] * acc[i][3][r];
            s += __shfl_xor(s, 1); q += __shfl_xor(q, 1);
            s += __shfl_xor(s, 2); q += __shfl_xor(q, 2);
            s += __shfl_xor(s, 4); q += __shfl_xor(q, 4);
            s += __shfl_xor(s, 8); q += __shfl_xor(q, 8);
            if (ln == 0) {
                int row = rt_base + i * 16 + quad * 4 + r;
                red[row][half][0] = s;
                red[row][half][1] = q;
            }
        }
    __syncthreads();

    float gv[4], bv[4];
    #pragma unroll
    for (int c = 0; c < 4; ++c) {
        int col = ct_base + c * 16 + ln;
        gv[c] = g[col]; bv[c] = bln[col];
    }
    #pragma unroll
    for (int i = 0; i < 2; ++i)
        #pragma unroll
        for (int r = 0; r < 4; ++r) {
            int row = rt_base + i * 16 + quad * 4 + r;
            float s = red[row][0][0] + red[row][1][0];
            float q = red[row][0][1] + red[row][1][1];
            float m = s * (1.0f / HD);
            float var = q * (1.0f / HD) - m * m;
            float rs = 1.0f / sqrtf(var + 1e-5f);
            #pragma unroll
            for (int c = 0; c < 4; ++c) {
                int col = ct_base + c * 16 + ln;
                float v = (acc[i][c][r] - m) * rs * gv[c] + bv[c];
                h16[(size_t)(base + row) * HD + col] = (f16)v;
            }
        }
}

// ---------------------------------------------------------------------------
// Decoder stage 1: per-channel upsample 1->4 + LN(4) + scatter-add to mesh.
// ---------------------------------------------------------------------------
__global__ __launch_bounds__(256)
void dec_up_kernel(const f16* __restrict__ h, const int* __restrict__ conn,
                   const float* __restrict__ uw1, const float* __restrict__ ub1,
                   const float* __restrict__ uw2, const float* __restrict__ ub2,
                   const float* __restrict__ uw3,
                   const float* __restrict__ ulng, const float* __restrict__ ulnb,
                   float* __restrict__ outn) {
    int idx = blockIdx.x * 256 + threadIdx.x;    // 0 .. NTOT*HD-1
    int n = idx >> 7, c = idx & 127;
    int b = n / NE, e = n - b * NE;
    float s = (float)h[idx];
    float u1[4], u2[4], u3[4];
    #pragma unroll
    for (int o = 0; o < 4; ++o) u1[o] = lrelu(s * uw1[c * 4 + o] + ub1[c * 4 + o]);
    #pragma unroll
    for (int o = 0; o < 4; ++o) {
        float a = ub2[c * 4 + o];
        #pragma unroll
        for (int i = 0; i < 4; ++i) a += u1[i] * uw2[c * 16 + i * 4 + o];
        u2[o] = lrelu(a);
    }
    #pragma unroll
    for (int o = 0; o < 4; ++o) {
        float a = 0.f;
        #pragma unroll
        for (int i = 0; i < 4; ++i) a += u2[i] * uw3[c * 16 + i * 4 + o];
        u3[o] = a;
    }
    float m = 0.25f * (u3[0] + u3[1] + u3[2] + u3[3]);
    float var = 0.f;
    #pragma unroll
    for (int o = 0; o < 4; ++o) { float d = u3[o] - m; var += d * d; }
    var *= 0.25f;
    float rs = 1.0f / sqrtf(var + 1e-5f);
    #pragma unroll
    for (int o = 0; o < 4; ++o) {
        float val = (u3[o] - m) * rs * ulng[c * 4 + o] + ulnb[c * 4 + o];
        int nd = conn[e * 4 + o];
        atomicAdd(&outn[((size_t)b * NN + nd) * HD + c], val);
    }
}

// ---------------------------------------------------------------------------
// Decoder stage 2: per mesh row H->3->3->3, one wave per row
// ---------------------------------------------------------------------------
__global__ __launch_bounds__(256)
void dec_out_kernel(const float* __restrict__ outn,
                    const float* __restrict__ cw1, const float* __restrict__ cb1,
                    const float* __restrict__ cw2, const float* __restrict__ cb2,
                    const float* __restrict__ cw3,
                    float* __restrict__ o, int nrows) {
    int r = blockIdx.x * 4 + (threadIdx.x >> 6);
    if (r >= nrows) return;
    int lane = threadIdx.x & 63;
    float v1 = outn[(size_t)r * HD + lane];
    float v2 = outn[(size_t)r * HD + 64 + lane];
    float s[3];
    #pragma unroll
    for (int c = 0; c < 3; ++c)
        s[c] = v1 * cw1[lane * 3 + c] + v2 * cw1[(lane + 64) * 3 + c];
    #pragma unroll
    for (int off = 32; off >= 1; off >>= 1) {
        s[0] += __shfl_down(s[0], off);
        s[1] += __shfl_down(s[1], off);
        s[2] += __shfl_down(s[2], off);
    }
    if (lane == 0) {
        float t1[3], t2[3];
        #pragma unroll
        for (int c = 0; c < 3; ++c) t1[c] = lrelu(s[c] + cb1[c]);
        #pragma unroll
        for (int c = 0; c < 3; ++c) {
            float a = cb2[c];
            #pragma unroll
            for (int k = 0; k < 3; ++k) a += t1[k] * cw2[k * 3 + c];
            t2[c] = lrelu(a);
        }
        #pragma unroll
        for (int c = 0; c < 3; ++c) {
            float a = 0.f;
            #pragma unroll
            for (int k = 0; k < 3; ++k) a += t2[k] * cw3[k * 3 + c];
            o[(size_t)r * 3 + c] = a;
        }
    }
}

// ---------------------------------------------------------------------------
extern "C" void kernel_launch(void* const* d_in, const int* in_sizes, int n_in,
                              void* d_out, int out_size, void* d_ws, size_t ws_size,
                              hipStream_t stream) {
    const int* elem_conn = (const int*)d_in[1];
    const int* edge_index = (const int*)d_in[2];
    const int* e_src = edge_index;          // row 0
    const int* e_dst = edge_index + NEDGE;  // row 1
    const float* enc_clnb = (const float*)d_in[9];
    const float* enc_ew1 = (const float*)d_in[10];
    const float* enc_eb1 = (const float*)d_in[11];
    const float* enc_ew2 = (const float*)d_in[12];
    const float* enc_eb2 = (const float*)d_in[13];
    const float* enc_ew3 = (const float*)d_in[14];
    const float* enc_elng = (const float*)d_in[15];
    const float* enc_elnb = (const float*)d_in[16];
    const float* p_ew1 = (const float*)d_in[17];
    const float* p_eb1 = (const float*)d_in[18];
    const float* p_ew2 = (const float*)d_in[19];
    const float* p_eb2 = (const float*)d_in[20];
    const float* p_ew3 = (const float*)d_in[21];
    const float* p_elng = (const float*)d_in[22];
    const float* p_elnb = (const float*)d_in[23];
    const float* p_nw1 = (const float*)d_in[24];
    const float* p_nb1 = (const float*)d_in[25];
    const float* p_nw2 = (const float*)d_in[26];
    const float* p_nb2 = (const float*)d_in[27];
    const float* p_nw3 = (const float*)d_in[28];
    const float* p_nlng = (const float*)d_in[29];
    const float* p_nlnb = (const float*)d_in[30];
    const float* dec_uw1 = (const float*)d_in[31];
    const float* dec_ub1 = (const float*)d_in[32];
    const float* dec_uw2 = (const float*)d_in[33];
    const float* dec_ub2 = (const float*)d_in[34];
    const float* dec_uw3 = (const float*)d_in[35];
    const float* dec_ulng = (const float*)d_in[36];
    const float* dec_ulnb = (const float*)d_in[37];
    const float* dec_cw1 = (const float*)d_in[38];
    const float* dec_cb1 = (const float*)d_in[39];
    const float* dec_cw2 = (const float*)d_in[40];
    const float* dec_cb2 = (const float*)d_in[41];
    const float* dec_cw3 = (const float*)d_in[42];

    // Workspace (bytes): h16 9.83M | wbuf 1.57M | hv0 | P1 9.83M | P2 9.83M |
    // aggr fp32 19.66M. outn (fp32 20.4M) overlays P1/P2/head-of-aggr at
    // decode time (all dead). Total 50.7 MB.
    char* ws = (char*)d_ws;
    f16* h16 = (f16*)(ws);
    f16* wbuf = (f16*)(ws + 9830400);
    float* hv0 = (float*)(ws + 11403264);
    f16* P1 = (f16*)(ws + 11403776);
    f16* P2 = (f16*)(ws + 21234176);
    float* aggr = (float*)(ws + 31064576);
    float* outn = (float*)(ws + 11403776);

    enc_const_kernel<<<1, 128, 0, stream>>>(enc_clnb, enc_ew1, enc_eb1, enc_ew2,
                                            enc_eb2, enc_ew3, enc_elng, enc_elnb, hv0);
    init_h16_kernel<<<1200, 256, 0, stream>>>(h16, hv0, NTOT * HD / 8);
    conv_weights_kernel<<<48, 256, 0, stream>>>(p_ew1, p_ew2, p_ew3,
                                                p_nw1, p_nw2, p_nw3, wbuf);

    for (int d = 0; d < DBLK; ++d) {
        const f16* ws_d = wbuf + (size_t)d * 8 * HD * HD;
        hipMemsetAsync(aggr, 0, (size_t)NTOT * HD * sizeof(float), stream);
        p_pre_kernel<<<NTOT / 64, 256, 0, stream>>>(
            h16, ws_d + 0 * HD * HD, ws_d + 1 * HD * HD, P1, P2);
        gn_edge<<<NEDGE / 64, 256, 0, stream>>>(
            P1, P2, e_dst, e_src,
            ws_d + 2 * HD * HD, ws_d + 3 * HD * HD,
            p_eb1 + (size_t)d * HD, p_eb2 + (size_t)d * HD,
            p_elng + (size_t)d * HD, p_elnb + (size_t)d * HD, aggr);
        gn_node<<<NTOT / 64, 256, 0, stream>>>(
            h16, aggr,
            ws_d + 4 * HD * HD, ws_d + 5 * HD * HD, ws_d + 6 * HD * HD, ws_d + 7 * HD * HD,
            p_nb1 + (size_t)d * HD, p_nb2 + (size_t)d * HD,
            p_nlng + (size_t)d * HD, p_nlnb + (size_t)d * HD);
    }
    // final h is in h16 (node writes in-place)
    hipMemsetAsync(outn, 0, (size_t)NMESH * HD * sizeof(float), stream);
    dec_up_kernel<<<NTOT * HD / 256, 256, 0, stream>>>(h16, elem_conn, dec_uw1, dec_ub1,
                                                       dec_uw2, dec_ub2, dec_uw3,
                                                       dec_ulng, dec_ulnb, outn);
    dec_out_kernel<<<(NMESH + 3) / 4, 256, 0, stream>>>(outn, dec_cw1, dec_cb1,
                                                        dec_cw2, dec_cb2, dec_cw3,
                                                        (float*)d_out, NMESH);
}

// Round 7
// 738.606 us; speedup vs baseline: 1.7091x; 1.3577x over previous
//
#include <hip/hip_runtime.h>
#include <hip/hip_fp16.h>
#include <math.h>

// Problem constants (from reference)
#define BS    8
#define NE    4800
#define NN    4981
#define CIN   3
#define HD    128      // H
#define DBLK  6        // D processor blocks
#define NEDGE 153600   // BS*EPG
#define NTOT  38400    // BS*NE (graph nodes)
#define NMESH (BS*NN)  // 39848 mesh rows

typedef _Float16 f16;
typedef _Float16 f16x8 __attribute__((ext_vector_type(8)));
typedef float f32x4 __attribute__((ext_vector_type(4)));

__device__ __forceinline__ float lrelu(float x) { return x >= 0.0f ? x : 0.2f * x; }

// ---------------------------------------------------------------------------
// K0: hv0 = ln(mlp(enc_clnb_row, enc_ew1..3), enc_elng, enc_elnb)
// Conv encoder + LayerNorm over size-1 axis collapses exactly to enc_clnb.
// ---------------------------------------------------------------------------
__global__ __launch_bounds__(128)
void enc_const_kernel(const float* __restrict__ clnb,
                      const float* __restrict__ ew1, const float* __restrict__ eb1,
                      const float* __restrict__ ew2, const float* __restrict__ eb2,
                      const float* __restrict__ ew3,
                      const float* __restrict__ g, const float* __restrict__ b,
                      float* __restrict__ hv0) {
    __shared__ float s1[HD], s2[HD], s3[HD];
    int j = threadIdx.x;
    float a = eb1[j];
    for (int c = 0; c < CIN; ++c) a += clnb[c] * ew1[c * HD + j];
    s1[j] = lrelu(a);
    __syncthreads();
    a = eb2[j];
    for (int k = 0; k < HD; ++k) a += s1[k] * ew2[k * HD + j];
    s2[j] = lrelu(a);
    __syncthreads();
    a = 0.0f;
    for (int k = 0; k < HD; ++k) a += s2[k] * ew3[k * HD + j];
    s3[j] = a;
    __syncthreads();
    float m = 0.0f;
    for (int k = 0; k < HD; ++k) m += s3[k];
    m *= (1.0f / HD);
    float v = 0.0f;
    for (int k = 0; k < HD; ++k) { float d = s3[k] - m; v += d * d; }
    v *= (1.0f / HD);
    float rs = 1.0f / sqrtf(v + 1e-5f);
    hv0[j] = (s3[j] - m) * rs * g[j] + b[j];
}

// d=0 edge message: m0 = ln(mlp([h0;h0]), elng0, elnb0). Exact identity:
// at d=0 all node rows equal h0, so every edge message equals m0 and
// aggr[n] = deg(n) * m0.
__global__ __launch_bounds__(128)
void msg0_kernel(const float* __restrict__ hv0,
                 const float* __restrict__ ew1, const float* __restrict__ eb1,
                 const float* __restrict__ ew2, const float* __restrict__ eb2,
                 const float* __restrict__ ew3,
                 const float* __restrict__ g, const float* __restrict__ b,
                 float* __restrict__ m0) {
    __shared__ float s1[HD], s2[HD], s3[HD];
    int j = threadIdx.x;
    float a = eb1[j];
    for (int k = 0; k < HD; ++k) a += hv0[k] * (ew1[k * HD + j] + ew1[(k + HD) * HD + j]);
    s1[j] = lrelu(a);
    __syncthreads();
    a = eb2[j];
    for (int k = 0; k < HD; ++k) a += s1[k] * ew2[k * HD + j];
    s2[j] = lrelu(a);
    __syncthreads();
    a = 0.0f;
    for (int k = 0; k < HD; ++k) a += s2[k] * ew3[k * HD + j];
    s3[j] = a;
    __syncthreads();
    float m = 0.0f;
    for (int k = 0; k < HD; ++k) m += s3[k];
    m *= (1.0f / HD);
    float v = 0.0f;
    for (int k = 0; k < HD; ++k) { float d = s3[k] - m; v += d * d; }
    v *= (1.0f / HD);
    float rs = 1.0f / sqrtf(v + 1e-5f);
    m0[j] = (s3[j] - m) * rs * g[j] + b[j];
}

// Broadcast hv0 (fp32) to all NTOT node rows as f16
__global__ __launch_bounds__(256)
void init_h16_kernel(f16* __restrict__ h, const float* __restrict__ hv0, int n8) {
    __shared__ f16 v[HD];
    if (threadIdx.x < HD) v[threadIdx.x] = (f16)hv0[threadIdx.x];
    __syncthreads();
    for (int i = blockIdx.x * blockDim.x + threadIdx.x; i < n8; i += gridDim.x * blockDim.x)
        ((uint4*)h)[i] = ((const uint4*)v)[i & 15];
}

// ---------------------------------------------------------------------------
// Convert + transpose processor weights to f16 Wt[n][k] layout.
// ---------------------------------------------------------------------------
__global__ __launch_bounds__(256)
void conv_weights_kernel(const float* __restrict__ ew1, const float* __restrict__ ew2,
                         const float* __restrict__ ew3,
                         const float* __restrict__ nw1, const float* __restrict__ nw2,
                         const float* __restrict__ nw3, f16* __restrict__ wbuf) {
    int b = blockIdx.x;        // 0..47
    int d = b >> 3, m = b & 7;
    const float* src;
    switch (m) {
        case 0: src = ew1 + (size_t)d * 2 * HD * HD; break;
        case 1: src = ew1 + (size_t)d * 2 * HD * HD + HD * HD; break;
        case 2: src = ew2 + (size_t)d * HD * HD; break;
        case 3: src = ew3 + (size_t)d * HD * HD; break;
        case 4: src = nw1 + (size_t)d * 2 * HD * HD; break;
        case 5: src = nw1 + (size_t)d * 2 * HD * HD + HD * HD; break;
        case 6: src = nw2 + (size_t)d * HD * HD; break;
        default: src = nw3 + (size_t)d * HD * HD; break;
    }
    f16* out = wbuf + (size_t)b * HD * HD;
    for (int idx = threadIdx.x; idx < HD * HD; idx += 256) {
        int n = idx >> 7, k = idx & 127;
        out[idx] = (f16)src[k * HD + n];   // Wt[n][k] = W[k][n]
    }
}

// ---------------------------------------------------------------------------
// CSR build: counting sort of edges by dest. edge_index is identical every
// call; rebuilt each launch (same work every call, graph-capture safe).
// ---------------------------------------------------------------------------
__global__ __launch_bounds__(256)
void csr_hist(const int* __restrict__ dest, int* __restrict__ deg) {
    int e = blockIdx.x * 256 + threadIdx.x;
    atomicAdd(&deg[dest[e]], 1);
}

__global__ __launch_bounds__(256)
void csr_scan1(const int* __restrict__ deg, int* __restrict__ rowptr,
               int* __restrict__ bsum) {
    __shared__ int s[256];
    int i = blockIdx.x * 256 + threadIdx.x;
    int v = deg[i];
    s[threadIdx.x] = v;
    __syncthreads();
    for (int off = 1; off < 256; off <<= 1) {
        int t = (threadIdx.x >= off) ? s[threadIdx.x - off] : 0;
        __syncthreads();
        s[threadIdx.x] += t;
        __syncthreads();
    }
    rowptr[i] = s[threadIdx.x] - v;          // exclusive
    if (threadIdx.x == 255) bsum[blockIdx.x] = s[255];
}

__global__ __launch_bounds__(256)
void csr_scan2(int* __restrict__ bsum, int nb) {
    __shared__ int s[256];
    int v = (threadIdx.x < nb) ? bsum[threadIdx.x] : 0;
    s[threadIdx.x] = v;
    __syncthreads();
    for (int off = 1; off < 256; off <<= 1) {
        int t = (threadIdx.x >= off) ? s[threadIdx.x - off] : 0;
        __syncthreads();
        s[threadIdx.x] += t;
        __syncthreads();
    }
    if (threadIdx.x < nb) bsum[threadIdx.x] = s[threadIdx.x] - v;   // exclusive
}

__global__ __launch_bounds__(256)
void csr_scan3(int* __restrict__ rowptr, const int* __restrict__ bsum) {
    int i = blockIdx.x * 256 + threadIdx.x;
    rowptr[i] += bsum[blockIdx.x];
}

__global__ __launch_bounds__(256)
void csr_scatter(const int* __restrict__ dest, const int* __restrict__ srcv,
                 const int* __restrict__ rowptr, int* __restrict__ cursor,
                 int* __restrict__ dsorted, int* __restrict__ ssorted) {
    int e = blockIdx.x * 256 + threadIdx.x;
    int d = dest[e];
    int pos = rowptr[d] + atomicAdd(&cursor[d], 1);
    dsorted[pos] = d;
    ssorted[pos] = srcv[e];
}

// ---------------------------------------------------------------------------
// Shared GEMM helpers. Tile 64 rows x 128 cols, 4 waves; wave w: rows
// (w>>1)*32, cols (w&1)*64, 2x4 grid of 16x16x32 MFMA.
// A[m=lane&15][k=quad*8+j], C/D col=lane&15, row=quad*4+reg (guide-verified).
// ---------------------------------------------------------------------------
__device__ __forceinline__ void stage_w(const f16* __restrict__ Wg, f16 (*Bt)[HD + 8],
                                        int tid) {
    #pragma unroll
    for (int t = 0; t < 8; ++t) {
        int idx = tid + t * 256;            // 0..2047 16B chunks of 128x128 f16
        int r = idx >> 4, c = (idx & 15) * 8;
        *(uint4*)(&Bt[r][c]) = *(const uint4*)(Wg + (size_t)r * HD + c);
    }
}

__device__ __forceinline__ void mfma_pass(const f16 (*A)[HD + 8], const f16 (*Bt)[HD + 8],
                                          int rt_base, int ct_base, int ln, int quad,
                                          f32x4 acc[2][4]) {
    #pragma unroll
    for (int ks = 0; ks < 4; ++ks) {
        int kb = ks * 32 + quad * 8;
        f16x8 a0 = *(const f16x8*)(&A[rt_base + ln][kb]);
        f16x8 a1 = *(const f16x8*)(&A[rt_base + 16 + ln][kb]);
        #pragma unroll
        for (int c = 0; c < 4; ++c) {
            f16x8 b = *(const f16x8*)(&Bt[ct_base + c * 16 + ln][kb]);
            acc[0][c] = __builtin_amdgcn_mfma_f32_16x16x32_f16(a0, b, acc[0][c], 0, 0, 0);
            acc[1][c] = __builtin_amdgcn_mfma_f32_16x16x32_f16(a1, b, acc[1][c], 0, 0, 0);
        }
    }
}

// ---------------------------------------------------------------------------
// Edge kernel (d>=1), dest-sorted order: act1 = lrelu(P1[d]+P2[s]+b1), W2,
// W3 passes, LN, then PLAIN coalesced f16 store to msg[slot] (no atomics).
// dest-gathers have ~4-way run-length locality (sorted). LDS 53.8 KB -> 3/CU.
// ---------------------------------------------------------------------------
__global__ __launch_bounds__(256, 3)
void gn_edge(const f16* __restrict__ P1, const f16* __restrict__ P2,
             const int* __restrict__ dsorted, const int* __restrict__ ssorted,
             const f16* __restrict__ W2, const f16* __restrict__ W3,
             const float* __restrict__ b1, const float* __restrict__ b2,
             const float* __restrict__ g, const float* __restrict__ bln,
             f16* __restrict__ msg) {
    __shared__ __align__(16) f16 As[64][HD + 8];
    __shared__ __align__(16) f16 Bt[HD][HD + 8];
    __shared__ float red[64][2][2];
    __shared__ int dS[64], sS[64];

    const int tid = threadIdx.x;
    const int base = blockIdx.x * 64;
    const int wave = tid >> 6, lane = tid & 63;
    const int ln = lane & 15, quad = lane >> 4;
    const int rt_base = (wave >> 1) * 32;
    const int ct_base = (wave & 1) * 64;
    const int half = wave & 1;

    if (tid < 64) dS[tid] = dsorted[base + tid];
    else if (tid < 128) sS[tid - 64] = ssorted[base + tid - 64];
    __syncthreads();

    stage_w(W2, Bt, tid);
    #pragma unroll
    for (int t = 0; t < 4; ++t) {
        int idx = tid + t * 256;            // 0..1023
        int r = idx >> 4, c = (idx & 15) * 8;
        f16x8 p1 = *(const f16x8*)(P1 + (size_t)dS[r] * HD + c);
        f16x8 p2 = *(const f16x8*)(P2 + (size_t)sS[r] * HD + c);
        float4 ba = *(const float4*)(b1 + c);
        float4 bb = *(const float4*)(b1 + c + 4);
        f16x8 o;
        o[0] = (f16)lrelu((float)p1[0] + (float)p2[0] + ba.x);
        o[1] = (f16)lrelu((float)p1[1] + (float)p2[1] + ba.y);
        o[2] = (f16)lrelu((float)p1[2] + (float)p2[2] + ba.z);
        o[3] = (f16)lrelu((float)p1[3] + (float)p2[3] + ba.w);
        o[4] = (f16)lrelu((float)p1[4] + (float)p2[4] + bb.x);
        o[5] = (f16)lrelu((float)p1[5] + (float)p2[5] + bb.y);
        o[6] = (f16)lrelu((float)p1[6] + (float)p2[6] + bb.z);
        o[7] = (f16)lrelu((float)p1[7] + (float)p2[7] + bb.w);
        *(f16x8*)(&As[r][c]) = o;
    }
    __syncthreads();

    f32x4 acc[2][4];

    // ---- Layer 2
    #pragma unroll
    for (int c = 0; c < 4; ++c) {
        float bj = b2[ct_base + c * 16 + ln];
        f32x4 bb = {bj, bj, bj, bj};
        acc[0][c] = bb; acc[1][c] = bb;
    }
    mfma_pass(As, Bt, rt_base, ct_base, ln, quad, acc);
    __syncthreads();
    stage_w(W3, Bt, tid);
    #pragma unroll
    for (int i = 0; i < 2; ++i)
        #pragma unroll
        for (int c = 0; c < 4; ++c)
            #pragma unroll
            for (int r = 0; r < 4; ++r)
                As[rt_base + i * 16 + quad * 4 + r][ct_base + c * 16 + ln] =
                    (f16)lrelu(acc[i][c][r]);
    __syncthreads();

    // ---- Layer 3
    #pragma unroll
    for (int c = 0; c < 4; ++c) { f32x4 z = {0,0,0,0}; acc[0][c] = z; acc[1][c] = z; }
    mfma_pass(As, Bt, rt_base, ct_base, ln, quad, acc);

    // ---- LayerNorm stats
    #pragma unroll
    for (int i = 0; i < 2; ++i)
        #pragma unroll
        for (int r = 0; r < 4; ++r) {
            float s = acc[i][0][r] + acc[i][1][r] + acc[i][2][r] + acc[i][3][r];
            float q = acc[i][0][r] * acc[i][0][r] + acc[i][1][r] * acc[i][1][r] +
                      acc[i][2][r] * acc[i][2][r] + acc[i][3][r] * acc[i][3][r];
            s += __shfl_xor(s, 1); q += __shfl_xor(q, 1);
            s += __shfl_xor(s, 2); q += __shfl_xor(q, 2);
            s += __shfl_xor(s, 4); q += __shfl_xor(q, 4);
            s += __shfl_xor(s, 8); q += __shfl_xor(q, 8);
            if (ln == 0) {
                int row = rt_base + i * 16 + quad * 4 + r;
                red[row][half][0] = s;
                red[row][half][1] = q;
            }
        }
    __syncthreads();

    // ---- Epilogue: LN scale + plain f16 store to msg (sorted slot order)
    float gv[4], bv[4];
    #pragma unroll
    for (int c = 0; c < 4; ++c) {
        int col = ct_base + c * 16 + ln;
        gv[c] = g[col]; bv[c] = bln[col];
    }
    #pragma unroll
    for (int i = 0; i < 2; ++i)
        #pragma unroll
        for (int r = 0; r < 4; ++r) {
            int row = rt_base + i * 16 + quad * 4 + r;
            float s = red[row][0][0] + red[row][1][0];
            float q = red[row][0][1] + red[row][1][1];
            float m = s * (1.0f / HD);
            float var = q * (1.0f / HD) - m * m;
            float rs = 1.0f / sqrtf(var + 1e-5f);
            #pragma unroll
            for (int c = 0; c < 4; ++c) {
                int col = ct_base + c * 16 + ln;
                float v = (acc[i][c][r] - m) * rs * gv[c] + bv[c];
                msg[(size_t)(base + row) * HD + col] = (f16)v;
            }
        }
}

// ---------------------------------------------------------------------------
// Node kernel. AGGR=0: aggr row = deg(n)*m0 (exact d=0 identity).
// AGGR=1: aggr row = fp32 sum of this node's contiguous msg rows (CSR).
// PROD: also emit P1 = h_new@nextW1a, P2 = h_new@nextW1b for the next edge
// stage (h_new already in LDS -> saves the separate p_pre kernel + h reload).
// Writes h16 in-place (block touches only its own rows). LDS 70 KB -> 2/CU.
// ---------------------------------------------------------------------------
template <int AGGR, bool PROD>
__global__ __launch_bounds__(256, 2)
void gn_node(f16* __restrict__ h16, const f16* __restrict__ msg,
             const int* __restrict__ rowptr, const int* __restrict__ deg,
             const float* __restrict__ m0,
             const f16* __restrict__ W1a, const f16* __restrict__ W1b,
             const f16* __restrict__ W2, const f16* __restrict__ W3,
             const float* __restrict__ b1, const float* __restrict__ b2,
             const float* __restrict__ g, const float* __restrict__ bln,
             const f16* __restrict__ nW1a, const f16* __restrict__ nW1b,
             f16* __restrict__ P1, f16* __restrict__ P2) {
    __shared__ __align__(16) f16 As1[64][HD + 8];
    __shared__ __align__(16) f16 As2[64][HD + 8];
    __shared__ __align__(16) f16 Bt[HD][HD + 8];
    __shared__ float red[64][2][2];
    __shared__ float m0s[HD];
    __shared__ int rpS[64], dgS[64];

    const int tid = threadIdx.x;
    const int base = blockIdx.x * 64;
    const int wave = tid >> 6, lane = tid & 63;
    const int ln = lane & 15, quad = lane >> 4;
    const int rt_base = (wave >> 1) * 32;
    const int ct_base = (wave & 1) * 64;
    const int half = wave & 1;

    if (AGGR == 0) {
        if (tid < HD) m0s[tid] = m0[tid];
        if (tid < 64) dgS[tid] = deg[base + tid];
    } else {
        if (tid < 64) { rpS[tid] = rowptr[base + tid]; dgS[tid] = deg[base + tid]; }
    }
    __syncthreads();

    // ---- Stage As1 = h rows, As2 = aggregated messages
    #pragma unroll
    for (int t = 0; t < 4; ++t) {
        int idx = tid + t * 256;            // 0..1023
        int r = idx >> 4, c = (idx & 15) * 8;
        *(uint4*)(&As1[r][c]) = *(const uint4*)(h16 + (size_t)(base + r) * HD + c);
        if (AGGR == 0) {
            float sc = (float)dgS[r];
            f16x8 o;
            #pragma unroll
            for (int u = 0; u < 8; ++u) o[u] = (f16)(sc * m0s[c + u]);
            *(f16x8*)(&As2[r][c]) = o;
        } else {
            int rp = rpS[r], dg = dgS[r];
            float a[8] = {0, 0, 0, 0, 0, 0, 0, 0};
            for (int j = 0; j < dg; ++j) {
                f16x8 mv = *(const f16x8*)(msg + (size_t)(rp + j) * HD + c);
                #pragma unroll
                for (int u = 0; u < 8; ++u) a[u] += (float)mv[u];
            }
            f16x8 o;
            #pragma unroll
            for (int u = 0; u < 8; ++u) o[u] = (f16)a[u];
            *(f16x8*)(&As2[r][c]) = o;
        }
    }
    stage_w(W1a, Bt, tid);
    __syncthreads();

    f32x4 acc[2][4];
    #pragma unroll
    for (int c = 0; c < 4; ++c) {
        float bj = b1[ct_base + c * 16 + ln];
        f32x4 bb = {bj, bj, bj, bj};
        acc[0][c] = bb; acc[1][c] = bb;
    }
    mfma_pass(As1, Bt, rt_base, ct_base, ln, quad, acc);
    __syncthreads();
    stage_w(W1b, Bt, tid);
    __syncthreads();
    mfma_pass(As2, Bt, rt_base, ct_base, ln, quad, acc);
    __syncthreads();
    stage_w(W2, Bt, tid);
    #pragma unroll
    for (int i = 0; i < 2; ++i)
        #pragma unroll
        for (int c = 0; c < 4; ++c)
            #pragma unroll
            for (int r = 0; r < 4; ++r)
                As1[rt_base + i * 16 + quad * 4 + r][ct_base + c * 16 + ln] =
                    (f16)lrelu(acc[i][c][r]);
    __syncthreads();

    #pragma unroll
    for (int c = 0; c < 4; ++c) {
        float bj = b2[ct_base + c * 16 + ln];
        f32x4 bb = {bj, bj, bj, bj};
        acc[0][c] = bb; acc[1][c] = bb;
    }
    mfma_pass(As1, Bt, rt_base, ct_base, ln, quad, acc);
    __syncthreads();
    stage_w(W3, Bt, tid);
    #pragma unroll
    for (int i = 0; i < 2; ++i)
        #pragma unroll
        for (int c = 0; c < 4; ++c)
            #pragma unroll
            for (int r = 0; r < 4; ++r)
                As2[rt_base + i * 16 + quad * 4 + r][ct_base + c * 16 + ln] =
                    (f16)lrelu(acc[i][c][r]);
    __syncthreads();

    #pragma unroll
    for (int c = 0; c < 4; ++c) { f32x4 z = {0,0,0,0}; acc[0][c] = z; acc[1][c] = z; }
    mfma_pass(As2, Bt, rt_base, ct_base, ln, quad, acc);

    #pragma unroll
    for (int i = 0; i < 2; ++i)
        #pragma unroll
        for (int r = 0; r < 4; ++r) {
            float s = acc[i][0][r] + acc[i][1][r] + acc[i][2][r] + acc[i][3][r];
            float q = acc[i][0][r] * acc[i][0][r] + acc[i][1][r] * acc[i][1][r] +
                      acc[i][2][r] * acc[i][2][r] + acc[i][3][r] * acc[i][3][r];
            s += __shfl_xor(s, 1); q += __shfl_xor(q, 1);
            s += __shfl_xor(s, 2); q += __shfl_xor(q, 2);
            s += __shfl_xor(s, 4); q += __shfl_xor(q, 4);
            s += __shfl_xor(s, 8); q += __shfl_xor(q, 8);
            if (ln == 0) {
                int row = rt_base + i * 16 + quad * 4 + r;
                red[row][half][0] = s;
                red[row][half][1] = q;
            }
        }
    __syncthreads();

    float gv[4], bv[4];
    #pragma unroll
    for (int c = 0; c < 4; ++c) {
        int col = ct_base + c * 16 + ln;
        gv[c] = g[col]; bv[c] = bln[col];
    }
    #pragma unroll
    for (int i = 0; i < 2; ++i)
        #pragma unroll
        for (int r = 0; r < 4; ++r) {
            int row = rt_base + i * 16 + quad * 4 + r;
            float s = red[row][0][0] + red[row][1][0];
            float q = red[row][0][1] + red[row][1][1];
            float m = s * (1.0f / HD);
            float var = q * (1.0f / HD) - m * m;
            float rs = 1.0f / sqrtf(var + 1e-5f);
            #pragma unroll
            for (int c = 0; c < 4; ++c) {
                int col = ct_base + c * 16 + ln;
                float v = (acc[i][c][r] - m) * rs * gv[c] + bv[c];
                f16 hv = (f16)v;
                h16[(size_t)(base + row) * HD + col] = hv;
                if (PROD) As1[row][col] = hv;    // h_new for P production
            }
        }

    if (PROD) {
        __syncthreads();                 // h_new in As1 visible; pass3 Bt reads done
        stage_w(nW1a, Bt, tid);
        __syncthreads();
        #pragma unroll
        for (int c = 0; c < 4; ++c) { f32x4 z = {0,0,0,0}; acc[0][c] = z; acc[1][c] = z; }
        mfma_pass(As1, Bt, rt_base, ct_base, ln, quad, acc);
        #pragma unroll
        for (int i = 0; i < 2; ++i)
            #pragma unroll
            for (int c = 0; c < 4; ++c)
                #pragma unroll
                for (int r = 0; r < 4; ++r)
                    P1[(size_t)(base + rt_base + i * 16 + quad * 4 + r) * HD +
                       ct_base + c * 16 + ln] = (f16)acc[i][c][r];
        __syncthreads();
        stage_w(nW1b, Bt, tid);
        __syncthreads();
        #pragma unroll
        for (int c = 0; c < 4; ++c) { f32x4 z = {0,0,0,0}; acc[0][c] = z; acc[1][c] = z; }
        mfma_pass(As1, Bt, rt_base, ct_base, ln, quad, acc);
        #pragma unroll
        for (int i = 0; i < 2; ++i)
            #pragma unroll
            for (int c = 0; c < 4; ++c)
                #pragma unroll
                for (int r = 0; r < 4; ++r)
                    P2[(size_t)(base + rt_base + i * 16 + quad * 4 + r) * HD +
                       ct_base + c * 16 + ln] = (f16)acc[i][c][r];
    }
}

// ---------------------------------------------------------------------------
// Decoder stage 1: per-channel upsample 1->4 + LN(4) + scatter-add to mesh.
// ---------------------------------------------------------------------------
__global__ __launch_bounds__(256)
void dec_up_kernel(const f16* __restrict__ h, const int* __restrict__ conn,
                   const float* __restrict__ uw1, const float* __restrict__ ub1,
                   const float* __restrict__ uw2, const float* __restrict__ ub2,
                   const float* __restrict__ uw3,
                   const float* __restrict__ ulng, const float* __restrict__ ulnb,
                   float* __restrict__ outn) {
    int idx = blockIdx.x * 256 + threadIdx.x;    // 0 .. NTOT*HD-1
    int n = idx >> 7, c = idx & 127;
    int b = n / NE, e = n - b * NE;
    float s = (float)h[idx];
    float u1[4], u2[4], u3[4];
    #pragma unroll
    for (int o = 0; o < 4; ++o) u1[o] = lrelu(s * uw1[c * 4 + o] + ub1[c * 4 + o]);
    #pragma unroll
    for (int o = 0; o < 4; ++o) {
        float a = ub2[c * 4 + o];
        #pragma unroll
        for (int i = 0; i < 4; ++i) a += u1[i] * uw2[c * 16 + i * 4 + o];
        u2[o] = lrelu(a);
    }
    #pragma unroll
    for (int o = 0; o < 4; ++o) {
        float a = 0.f;
        #pragma unroll
        for (int i = 0; i < 4; ++i) a += u2[i] * uw3[c * 16 + i * 4 + o];
        u3[o] = a;
    }
    float m = 0.25f * (u3[0] + u3[1] + u3[2] + u3[3]);
    float var = 0.f;
    #pragma unroll
    for (int o = 0; o < 4; ++o) { float d = u3[o] - m; var += d * d; }
    var *= 0.25f;
    float rs = 1.0f / sqrtf(var + 1e-5f);
    #pragma unroll
    for (int o = 0; o < 4; ++o) {
        float val = (u3[o] - m) * rs * ulng[c * 4 + o] + ulnb[c * 4 + o];
        int nd = conn[e * 4 + o];
        atomicAdd(&outn[((size_t)b * NN + nd) * HD + c], val);
    }
}

// ---------------------------------------------------------------------------
// Decoder stage 2: per mesh row H->3->3->3, one wave per row
// ---------------------------------------------------------------------------
__global__ __launch_bounds__(256)
void dec_out_kernel(const float* __restrict__ outn,
                    const float* __restrict__ cw1, const float* __restrict__ cb1,
                    const float* __restrict__ cw2, const float* __restrict__ cb2,
                    const float* __restrict__ cw3,
                    float* __restrict__ o, int nrows) {
    int r = blockIdx.x * 4 + (threadIdx.x >> 6);
    if (r >= nrows) return;
    int lane = threadIdx.x & 63;
    float v1 = outn[(size_t)r * HD + lane];
    float v2 = outn[(size_t)r * HD + 64 + lane];
    float s[3];
    #pragma unroll
    for (int c = 0; c < 3; ++c)
        s[c] = v1 * cw1[lane * 3 + c] + v2 * cw1[(lane + 64) * 3 + c];
    #pragma unroll
    for (int off = 32; off >= 1; off >>= 1) {
        s[0] += __shfl_down(s[0], off);
        s[1] += __shfl_down(s[1], off);
        s[2] += __shfl_down(s[2], off);
    }
    if (lane == 0) {
        float t1[3], t2[3];
        #pragma unroll
        for (int c = 0; c < 3; ++c) t1[c] = lrelu(s[c] + cb1[c]);
        #pragma unroll
        for (int c = 0; c < 3; ++c) {
            float a = cb2[c];
            #pragma unroll
            for (int k = 0; k < 3; ++k) a += t1[k] * cw2[k * 3 + c];
            t2[c] = lrelu(a);
        }
        #pragma unroll
        for (int c = 0; c < 3; ++c) {
            float a = 0.f;
            #pragma unroll
            for (int k = 0; k < 3; ++k) a += t2[k] * cw3[k * 3 + c];
            o[(size_t)r * 3 + c] = a;
        }
    }
}

// ---------------------------------------------------------------------------
extern "C" void kernel_launch(void* const* d_in, const int* in_sizes, int n_in,
                              void* d_out, int out_size, void* d_ws, size_t ws_size,
                              hipStream_t stream) {
    const int* elem_conn = (const int*)d_in[1];
    const int* edge_index = (const int*)d_in[2];
    const int* e_src = edge_index;          // row 0
    const int* e_dst = edge_index + NEDGE;  // row 1
    const float* enc_clnb = (const float*)d_in[9];
    const float* enc_ew1 = (const float*)d_in[10];
    const float* enc_eb1 = (const float*)d_in[11];
    const float* enc_ew2 = (const float*)d_in[12];
    const float* enc_eb2 = (const float*)d_in[13];
    const float* enc_ew3 = (const float*)d_in[14];
    const float* enc_elng = (const float*)d_in[15];
    const float* enc_elnb = (const float*)d_in[16];
    const float* p_ew1 = (const float*)d_in[17];
    const float* p_eb1 = (const float*)d_in[18];
    const float* p_ew2 = (const float*)d_in[19];
    const float* p_eb2 = (const float*)d_in[20];
    const float* p_ew3 = (const float*)d_in[21];
    const float* p_elng = (const float*)d_in[22];
    const float* p_elnb = (const float*)d_in[23];
    const float* p_nw1 = (const float*)d_in[24];
    const float* p_nb1 = (const float*)d_in[25];
    const float* p_nw2 = (const float*)d_in[26];
    const float* p_nb2 = (const float*)d_in[27];
    const float* p_nw3 = (const float*)d_in[28];
    const float* p_nlng = (const float*)d_in[29];
    const float* p_nlnb = (const float*)d_in[30];
    const float* dec_uw1 = (const float*)d_in[31];
    const float* dec_ub1 = (const float*)d_in[32];
    const float* dec_uw2 = (const float*)d_in[33];
    const float* dec_ub2 = (const float*)d_in[34];
    const float* dec_uw3 = (const float*)d_in[35];
    const float* dec_ulng = (const float*)d_in[36];
    const float* dec_ulnb = (const float*)d_in[37];
    const float* dec_cw1 = (const float*)d_in[38];
    const float* dec_cb1 = (const float*)d_in[39];
    const float* dec_cw2 = (const float*)d_in[40];
    const float* dec_cb2 = (const float*)d_in[41];
    const float* dec_cw3 = (const float*)d_in[42];

    // Workspace layout (bytes), total ~70.9 MB:
    char* ws = (char*)d_ws;
    f16*   h16     = (f16*)(ws);                        //  9,830,400
    f16*   wbuf    = (f16*)(ws + 9830400);              //  1,572,864
    float* hv0     = (float*)(ws + 11403264);           //  512
    float* m0      = (float*)(ws + 11403776);           //  512
    f16*   P1      = (f16*)(ws + 11404288);             //  9,830,400
    f16*   P2      = (f16*)(ws + 21234688);             //  9,830,400
    f16*   msg     = (f16*)(ws + 31065088);             // 39,321,600
    float* outn    = (float*)(ws + 31065088);           // overlays msg (20.4MB)
    int*   deg     = (int*)(ws + 70386688);             //  153,600
    int*   rowptr  = (int*)(ws + 70540288);             //  153,600
    int*   cursor  = (int*)(ws + 70693888);             //  153,600
    int*   bsum    = (int*)(ws + 70847488);             //  1,024
    int*   dsorted = (int*)(ws + 70848512);             //  614,400
    int*   ssorted = (int*)(ws + 71462912);             //  614,400

    // ---- Encoder constants + weight conversion
    enc_const_kernel<<<1, 128, 0, stream>>>(enc_clnb, enc_ew1, enc_eb1, enc_ew2,
                                            enc_eb2, enc_ew3, enc_elng, enc_elnb, hv0);
    init_h16_kernel<<<1200, 256, 0, stream>>>(h16, hv0, NTOT * HD / 8);
    conv_weights_kernel<<<48, 256, 0, stream>>>(p_ew1, p_ew2, p_ew3,
                                                p_nw1, p_nw2, p_nw3, wbuf);
    msg0_kernel<<<1, 128, 0, stream>>>(hv0, p_ew1, p_eb1, p_ew2, p_eb2, p_ew3,
                                       p_elng, p_elnb, m0);

    // ---- CSR build (edge_index is constant; rebuilt every call)
    hipMemsetAsync(deg, 0, NTOT * sizeof(int), stream);
    hipMemsetAsync(cursor, 0, NTOT * sizeof(int), stream);
    csr_hist<<<NEDGE / 256, 256, 0, stream>>>(e_dst, deg);
    csr_scan1<<<NTOT / 256, 256, 0, stream>>>(deg, rowptr, bsum);
    csr_scan2<<<1, 256, 0, stream>>>(bsum, NTOT / 256);
    csr_scan3<<<NTOT / 256, 256, 0, stream>>>(rowptr, bsum);
    csr_scatter<<<NEDGE / 256, 256, 0, stream>>>(e_dst, e_src, rowptr, cursor,
                                                 dsorted, ssorted);

    // ---- d=0: aggr = deg*m0 (exact); node + produce P for d=1
    {
        const f16* wd = wbuf;                       // d=0
        const f16* wn = wbuf + (size_t)8 * HD * HD; // d=1
        gn_node<0, true><<<NTOT / 64, 256, 0, stream>>>(
            h16, nullptr, nullptr, deg, m0,
            wd + 4 * HD * HD, wd + 5 * HD * HD, wd + 6 * HD * HD, wd + 7 * HD * HD,
            p_nb1, p_nb2, p_nlng, p_nlnb,
            wn + 0 * HD * HD, wn + 1 * HD * HD, P1, P2);
    }

    // ---- d=1..5
    for (int d = 1; d < DBLK; ++d) {
        const f16* wd = wbuf + (size_t)d * 8 * HD * HD;
        gn_edge<<<NEDGE / 64, 256, 0, stream>>>(
            P1, P2, dsorted, ssorted,
            wd + 2 * HD * HD, wd + 3 * HD * HD,
            p_eb1 + (size_t)d * HD, p_eb2 + (size_t)d * HD,
            p_elng + (size_t)d * HD, p_elnb + (size_t)d * HD, msg);
        if (d < DBLK - 1) {
            const f16* wn = wbuf + (size_t)(d + 1) * 8 * HD * HD;
            gn_node<1, true><<<NTOT / 64, 256, 0, stream>>>(
                h16, msg, rowptr, deg, nullptr,
                wd + 4 * HD * HD, wd + 5 * HD * HD, wd + 6 * HD * HD, wd + 7 * HD * HD,
                p_nb1 + (size_t)d * HD, p_nb2 + (size_t)d * HD,
                p_nlng + (size_t)d * HD, p_nlnb + (size_t)d * HD,
                wn + 0 * HD * HD, wn + 1 * HD * HD, P1, P2);
        } else {
            gn_node<1, false><<<NTOT / 64, 256, 0, stream>>>(
                h16, msg, rowptr, deg, nullptr,
                wd + 4 * HD * HD, wd + 5 * HD * HD, wd + 6 * HD * HD, wd + 7 * HD * HD,
                p_nb1 + (size_t)d * HD, p_nb2 + (size_t)d * HD,
                p_nlng + (size_t)d * HD, p_nlnb + (size_t)d * HD,
                wbuf, wbuf, P1, P2);
        }
    }

    // ---- Decoder (outn overlays msg; msg dead after last gn_node)
    hipMemsetAsync(outn, 0, (size_t)NMESH * HD * sizeof(float), stream);
    dec_up_kernel<<<NTOT * HD / 256, 256, 0, stream>>>(h16, elem_conn, dec_uw1, dec_ub1,
                                                       dec_uw2, dec_ub2, dec_uw3,
                                                       dec_ulng, dec_ulnb, outn);
    dec_out_kernel<<<(NMESH + 3) / 4, 256, 0, stream>>>(outn, dec_cw1, dec_cb1,
                                                        dec_cw2, dec_cb2, dec_cw3,
                                                        (float*)d_out, NMESH);
}